// Round 1
// baseline (2362.636 us; speedup 1.0000x reference)
//
#include <hip/hip_runtime.h>
#include <cstdint>
#include <cstddef>

#define B_ 4
#define L_ 2048
#define C_ 1024
#define H_ 16
#define D_ 64

// ---------------------------------------------------------------------------
// GEMM: C = A(MxK) @ B(KxN) + bias  (row-major, fp32)
// 128x128 block tile, BK=16, 256 threads, 8x8 micro-tile split as 2x float4
// chunks (cols {tx*4..+3} and {64+tx*4..+3}) so LDS reads are conflict-free
// ds_read_b128. M%128==0, N%128==0, K%16==0 hold for all our shapes.
// ---------------------------------------------------------------------------
__global__ __launch_bounds__(256) void gemm_bias_kernel(
    const float* __restrict__ A, const float* __restrict__ Bm,
    const float* __restrict__ bias, float* __restrict__ Cm,
    int M, int N, int K)
{
    __shared__ __align__(16) float As[16][132];
    __shared__ __align__(16) float Bs[16][132];
    const int tid = threadIdx.x;
    const int tx = tid & 15;
    const int ty = tid >> 4;
    const int brow = blockIdx.y * 128;
    const int bcol = blockIdx.x * 128;

    float acc[8][8] = {};

    for (int k0 = 0; k0 < K; k0 += 16) {
        // stage A tile (128x16) and B tile (16x128) into LDS, float4 loads
        #pragma unroll
        for (int t = 0; t < 2; t++) {
            int i = tid + t * 256;         // 0..511
            int m  = i >> 2;               // 0..127
            int k4 = (i & 3) * 4;          // 0,4,8,12
            float4 av = *(const float4*)&A[(size_t)(brow + m) * K + k0 + k4];
            As[k4 + 0][m] = av.x;
            As[k4 + 1][m] = av.y;
            As[k4 + 2][m] = av.z;
            As[k4 + 3][m] = av.w;
            int kk = i >> 5;               // 0..15
            int n4 = (i & 31) * 4;         // 0..124
            float4 bv = *(const float4*)&Bm[(size_t)(k0 + kk) * N + bcol + n4];
            *(float4*)&Bs[kk][n4] = bv;
        }
        __syncthreads();
        #pragma unroll
        for (int kk = 0; kk < 16; kk++) {
            float4 a0 = *(const float4*)&As[kk][ty * 4];
            float4 a1 = *(const float4*)&As[kk][64 + ty * 4];
            float4 b0 = *(const float4*)&Bs[kk][tx * 4];
            float4 b1 = *(const float4*)&Bs[kk][64 + tx * 4];
            float ar[8] = {a0.x, a0.y, a0.z, a0.w, a1.x, a1.y, a1.z, a1.w};
            float br[8] = {b0.x, b0.y, b0.z, b0.w, b1.x, b1.y, b1.z, b1.w};
            #pragma unroll
            for (int i = 0; i < 8; i++)
                #pragma unroll
                for (int j = 0; j < 8; j++)
                    acc[i][j] += ar[i] * br[j];
        }
        __syncthreads();
    }

    float4 bb0 = *(const float4*)&bias[bcol + tx * 4];
    float4 bb1 = *(const float4*)&bias[bcol + 64 + tx * 4];
    float br[8] = {bb0.x, bb0.y, bb0.z, bb0.w, bb1.x, bb1.y, bb1.z, bb1.w};
    #pragma unroll
    for (int i = 0; i < 8; i++) {
        int r = brow + ((i < 4) ? (ty * 4 + i) : (64 + ty * 4 + (i - 4)));
        float4 o0 = make_float4(acc[i][0] + br[0], acc[i][1] + br[1],
                                acc[i][2] + br[2], acc[i][3] + br[3]);
        float4 o1 = make_float4(acc[i][4] + br[4], acc[i][5] + br[5],
                                acc[i][6] + br[6], acc[i][7] + br[7]);
        *(float4*)&Cm[(size_t)r * N + bcol + tx * 4] = o0;
        *(float4*)&Cm[(size_t)r * N + bcol + 64 + tx * 4] = o1;
    }
}

// ---------------------------------------------------------------------------
// Per-head RMS norm of q and k rows, in place in the qkv buffer.
// One wave per (b,l,h,{q|k}) row of D=64. n = sqrt(sum t^2);
// out = t / max(n,1e-12) * gamma * sqrt(D)
// ---------------------------------------------------------------------------
__global__ __launch_bounds__(256) void rmsnorm_kernel(
    float* __restrict__ qkv, const float* __restrict__ q_gamma,
    const float* __restrict__ k_gamma)
{
    const int lane = threadIdx.x & 63;
    const int wid = blockIdx.x * 4 + (threadIdx.x >> 6);
    const int NROWS = B_ * L_ * H_;   // 131072
    int s, row;
    const float* gamma;
    if (wid < NROWS) { s = 0; row = wid; gamma = q_gamma; }
    else             { s = 1; row = wid - NROWS; gamma = k_gamma; }
    const int h  = row & 15;
    const int bl = row >> 4;
    const size_t idx = ((size_t)bl * 3 + s) * 1024 + h * 64 + lane;
    float v = qkv[idx];
    float ss = v * v;
    #pragma unroll
    for (int m = 1; m < 64; m <<= 1) ss += __shfl_xor(ss, m, 64);
    float n = sqrtf(ss);
    float denom = fmaxf(n, 1e-12f);
    qkv[idx] = (v / denom) * gamma[h * 64 + lane] * 8.0f;  // sqrt(64)=8
}

// ---------------------------------------------------------------------------
// Flash-style attention. One block = one (b,h) and a 64-row query tile.
// Streams 64-key K/V tiles; online softmax; O accumulated in registers.
// LDS layouts chosen so compute-phase reads are float4 (b128):
//   QsT[d][row], KsT[d][key], Vs[key][d], SsT[key][row]
// ---------------------------------------------------------------------------
__global__ __launch_bounds__(256) void attn_kernel(
    const float* __restrict__ qkv, float* __restrict__ hbuf)
{
    const int tid = threadIdx.x;
    const int tx = tid & 15;
    const int ty = tid >> 4;
    const int qt = blockIdx.x & 31;        // 32 q-tiles of 64
    const int h  = (blockIdx.x >> 5) & 15;
    const int b  = blockIdx.x >> 9;

    __shared__ __align__(16) float QsT[64][68];
    __shared__ __align__(16) float KsT[64][68];
    __shared__ __align__(16) float Vs[64][68];
    __shared__ __align__(16) float SsT[64][68];
    __shared__ __align__(16) float mrow[64];
    __shared__ __align__(16) float lrow[64];
    __shared__ __align__(16) float arow[64];

    const int q0 = qt * 64;
    const float scale = 0.125f;  // 1/sqrt(64)

    // load Q tile (transposed into QsT[d][row])
    for (int i = tid; i < 1024; i += 256) {
        int r  = i >> 4;
        int d4 = (i & 15) * 4;
        float4 qv = *(const float4*)&qkv[(size_t)(b * L_ + q0 + r) * 3072 + h * 64 + d4];
        QsT[d4 + 0][r] = qv.x;
        QsT[d4 + 1][r] = qv.y;
        QsT[d4 + 2][r] = qv.z;
        QsT[d4 + 3][r] = qv.w;
    }
    if (tid < 64) { mrow[tid] = -1e30f; lrow[tid] = 0.0f; }

    float acc[4][4] = {};
    __syncthreads();

    for (int j0 = 0; j0 < L_; j0 += 64) {
        // stage K (transposed) and V tiles
        for (int i = tid; i < 1024; i += 256) {
            int r  = i >> 4;
            int d4 = (i & 15) * 4;
            size_t base = (size_t)(b * L_ + j0 + r) * 3072 + h * 64 + d4;
            float4 kv = *(const float4*)&qkv[base + 1024];
            float4 vv = *(const float4*)&qkv[base + 2048];
            KsT[d4 + 0][r] = kv.x;
            KsT[d4 + 1][r] = kv.y;
            KsT[d4 + 2][r] = kv.z;
            KsT[d4 + 3][r] = kv.w;
            *(float4*)&Vs[r][d4] = vv;
        }
        __syncthreads();

        // S = Q @ K^T * scale   (each thread: 4 rows x 4 keys)
        float s[4][4] = {};
        #pragma unroll 8
        for (int d = 0; d < 64; d++) {
            float4 q4 = *(const float4*)&QsT[d][ty * 4];
            float4 k4 = *(const float4*)&KsT[d][tx * 4];
            float qr[4] = {q4.x, q4.y, q4.z, q4.w};
            float kr[4] = {k4.x, k4.y, k4.z, k4.w};
            #pragma unroll
            for (int i = 0; i < 4; i++)
                #pragma unroll
                for (int j = 0; j < 4; j++)
                    s[i][j] += qr[i] * kr[j];
        }
        #pragma unroll
        for (int j = 0; j < 4; j++) {
            float4 sc = make_float4(s[0][j] * scale, s[1][j] * scale,
                                    s[2][j] * scale, s[3][j] * scale);
            *(float4*)&SsT[tx * 4 + j][ty * 4] = sc;
        }
        __syncthreads();

        // online softmax per row (threads 0..63, one row each)
        if (tid < 64) {
            const int r = tid;
            float m_old = mrow[r];
            float mt = -1e30f;
            #pragma unroll 8
            for (int c = 0; c < 64; c++) mt = fmaxf(mt, SsT[c][r]);
            float m_new = fmaxf(m_old, mt);
            float alpha = __expf(m_old - m_new);
            float lsum = 0.0f;
            #pragma unroll 8
            for (int c = 0; c < 64; c++) {
                float e = __expf(SsT[c][r] - m_new);
                SsT[c][r] = e;
                lsum += e;
            }
            mrow[r] = m_new;
            lrow[r] = lrow[r] * alpha + lsum;
            arow[r] = alpha;
        }
        __syncthreads();

        // O = O*alpha + P @ V
        {
            float4 a4 = *(const float4*)&arow[ty * 4];
            float al[4] = {a4.x, a4.y, a4.z, a4.w};
            #pragma unroll
            for (int i = 0; i < 4; i++)
                #pragma unroll
                for (int j = 0; j < 4; j++)
                    acc[i][j] *= al[i];
        }
        #pragma unroll 8
        for (int k = 0; k < 64; k++) {
            float4 p4 = *(const float4*)&SsT[k][ty * 4];
            float4 v4 = *(const float4*)&Vs[k][tx * 4];
            float pr[4] = {p4.x, p4.y, p4.z, p4.w};
            float vr[4] = {v4.x, v4.y, v4.z, v4.w};
            #pragma unroll
            for (int i = 0; i < 4; i++)
                #pragma unroll
                for (int j = 0; j < 4; j++)
                    acc[i][j] += pr[i] * vr[j];
        }
        __syncthreads();
    }

    // epilogue: divide by l, write h[b, l, h*64+d]
    float4 l4 = *(const float4*)&lrow[ty * 4];
    float li[4] = {1.0f / l4.x, 1.0f / l4.y, 1.0f / l4.z, 1.0f / l4.w};
    #pragma unroll
    for (int i = 0; i < 4; i++) {
        int r = q0 + ty * 4 + i;
        float4 o = make_float4(acc[i][0] * li[i], acc[i][1] * li[i],
                               acc[i][2] * li[i], acc[i][3] * li[i]);
        *(float4*)&hbuf[(size_t)(b * L_ + r) * 1024 + h * 64 + tx * 4] = o;
    }
}

// ---------------------------------------------------------------------------
extern "C" void kernel_launch(void* const* d_in, const int* in_sizes, int n_in,
                              void* d_out, int out_size, void* d_ws, size_t ws_size,
                              hipStream_t stream)
{
    const float* x       = (const float*)d_in[0];
    const float* Wqkv    = (const float*)d_in[1];
    const float* bqkv    = (const float*)d_in[2];
    const float* q_gamma = (const float*)d_in[3];
    const float* k_gamma = (const float*)d_in[4];
    const float* Wout    = (const float*)d_in[5];
    const float* bout    = (const float*)d_in[6];
    float* out = (float*)d_out;

    float* qkv  = (float*)d_ws;                          // 8192*3072 fp32 = 96 MB
    float* hbuf = qkv + (size_t)B_ * L_ * 3 * C_;        // 8192*1024 fp32 = 32 MB

    // 1) qkv = x @ Wqkv + bqkv     (M=8192, N=3072, K=1024)
    gemm_bias_kernel<<<dim3(3 * C_ / 128, B_ * L_ / 128), 256, 0, stream>>>(
        x, Wqkv, bqkv, qkv, B_ * L_, 3 * C_, C_);

    // 2) RMS-norm q and k in place (2 * B*L*H rows, 4 waves/block)
    rmsnorm_kernel<<<2 * B_ * L_ * H_ / 4, 256, 0, stream>>>(qkv, q_gamma, k_gamma);

    // 3) flash attention -> hbuf   (B*H*(L/64) = 2048 blocks)
    attn_kernel<<<B_ * H_ * (L_ / 64), 256, 0, stream>>>(qkv, hbuf);

    // 4) out = hbuf @ Wout + bout  (M=8192, N=1024, K=1024)
    gemm_bias_kernel<<<dim3(C_ / 128, B_ * L_ / 128), 256, 0, stream>>>(
        hbuf, Wout, bout, out, B_ * L_, C_, C_);
}

// Round 2
// 1188.809 us; speedup vs baseline: 1.9874x; 1.9874x over previous
//
#include <hip/hip_runtime.h>
#include <hip/hip_bf16.h>
#include <cstdint>
#include <cstddef>

#define B_ 4
#define L_ 2048
#define C_ 1024
#define H_ 16
#define D_ 64

typedef __bf16 bf16x2 __attribute__((ext_vector_type(2)));
typedef __bf16 bf16x4 __attribute__((ext_vector_type(4)));
typedef __bf16 bf16x8 __attribute__((ext_vector_type(8)));
typedef float  f32x4  __attribute__((ext_vector_type(4)));

// ---------------------------------------------------------------------------
// GEMM: C = A(MxK) @ B(KxN) + bias  (row-major, fp32) — unchanged from R1.
// ---------------------------------------------------------------------------
__global__ __launch_bounds__(256) void gemm_bias_kernel(
    const float* __restrict__ A, const float* __restrict__ Bm,
    const float* __restrict__ bias, float* __restrict__ Cm,
    int M, int N, int K)
{
    __shared__ __align__(16) float As[16][132];
    __shared__ __align__(16) float Bs[16][132];
    const int tid = threadIdx.x;
    const int tx = tid & 15;
    const int ty = tid >> 4;
    const int brow = blockIdx.y * 128;
    const int bcol = blockIdx.x * 128;

    float acc[8][8] = {};

    for (int k0 = 0; k0 < K; k0 += 16) {
        #pragma unroll
        for (int t = 0; t < 2; t++) {
            int i = tid + t * 256;
            int m  = i >> 2;
            int k4 = (i & 3) * 4;
            float4 av = *(const float4*)&A[(size_t)(brow + m) * K + k0 + k4];
            As[k4 + 0][m] = av.x;
            As[k4 + 1][m] = av.y;
            As[k4 + 2][m] = av.z;
            As[k4 + 3][m] = av.w;
            int kk = i >> 5;
            int n4 = (i & 31) * 4;
            float4 bv = *(const float4*)&Bm[(size_t)(k0 + kk) * N + bcol + n4];
            *(float4*)&Bs[kk][n4] = bv;
        }
        __syncthreads();
        #pragma unroll
        for (int kk = 0; kk < 16; kk++) {
            float4 a0 = *(const float4*)&As[kk][ty * 4];
            float4 a1 = *(const float4*)&As[kk][64 + ty * 4];
            float4 b0 = *(const float4*)&Bs[kk][tx * 4];
            float4 b1 = *(const float4*)&Bs[kk][64 + tx * 4];
            float ar[8] = {a0.x, a0.y, a0.z, a0.w, a1.x, a1.y, a1.z, a1.w};
            float br[8] = {b0.x, b0.y, b0.z, b0.w, b1.x, b1.y, b1.z, b1.w};
            #pragma unroll
            for (int i = 0; i < 8; i++)
                #pragma unroll
                for (int j = 0; j < 8; j++)
                    acc[i][j] += ar[i] * br[j];
        }
        __syncthreads();
    }

    float4 bb0 = *(const float4*)&bias[bcol + tx * 4];
    float4 bb1 = *(const float4*)&bias[bcol + 64 + tx * 4];
    float br[8] = {bb0.x, bb0.y, bb0.z, bb0.w, bb1.x, bb1.y, bb1.z, bb1.w};
    #pragma unroll
    for (int i = 0; i < 8; i++) {
        int r = brow + ((i < 4) ? (ty * 4 + i) : (64 + ty * 4 + (i - 4)));
        float4 o0 = make_float4(acc[i][0] + br[0], acc[i][1] + br[1],
                                acc[i][2] + br[2], acc[i][3] + br[3]);
        float4 o1 = make_float4(acc[i][4] + br[4], acc[i][5] + br[5],
                                acc[i][6] + br[6], acc[i][7] + br[7]);
        *(float4*)&Cm[(size_t)r * N + bcol + tx * 4] = o0;
        *(float4*)&Cm[(size_t)r * N + bcol + 64 + tx * 4] = o1;
    }
}

// ---------------------------------------------------------------------------
// Per-head RMS norm of q and k rows, in place — unchanged from R1.
// ---------------------------------------------------------------------------
__global__ __launch_bounds__(256) void rmsnorm_kernel(
    float* __restrict__ qkv, const float* __restrict__ q_gamma,
    const float* __restrict__ k_gamma)
{
    const int lane = threadIdx.x & 63;
    const int wid = blockIdx.x * 4 + (threadIdx.x >> 6);
    const int NROWS = B_ * L_ * H_;
    int s, row;
    const float* gamma;
    if (wid < NROWS) { s = 0; row = wid; gamma = q_gamma; }
    else             { s = 1; row = wid - NROWS; gamma = k_gamma; }
    const int h  = row & 15;
    const int bl = row >> 4;
    const size_t idx = ((size_t)bl * 3 + s) * 1024 + h * 64 + lane;
    float v = qkv[idx];
    float ss = v * v;
    #pragma unroll
    for (int m = 1; m < 64; m <<= 1) ss += __shfl_xor(ss, m, 64);
    float n = sqrtf(ss);
    float denom = fmaxf(n, 1e-12f);
    qkv[idx] = (v / denom) * gamma[h * 64 + lane] * 8.0f;
}

// ---------------------------------------------------------------------------
// MFMA flash attention (bf16 inputs, fp32 accumulate).
// Block = (b, h, 64-row q-tile), 256 thr = 4 waves, wave w owns q-rows
// w*16..w*16+15. K-tiles of 64 keys.
//
// MFMA 16x16x32 bf16 layouts (verified m89):
//   A-frag: a[j] = A[m = lane&15][k = (lane>>4)*8 + j]
//   B-frag: b[j] = B^T[n = lane&15][k = (lane>>4)*8 + j]
//   C/D:    col = lane&15, row = (lane>>4)*4 + reg
// LDS layouts (row stride 72 bf16 = 144 B -> all frag reads are b128 with
// even 8-lanes-per-4-bank-group distribution = 8-cycle floor):
//   Qs[row][d] (Q pre-scaled by 1/8), Ks[key][d], Vt[d][key], Ps[row][key]
// QK^T: A=Q, B^T=K  -> S in C-layout (row=q-row, col=key)
// PV as O^T = V^T @ P^T: A=V^T (=Vt rows), B^T=P (=Ps rows)
//   -> O^T C-layout: row=d, col=q-row  => alpha/l are per-lane scalars,
//      epilogue is float4 stores.
// ---------------------------------------------------------------------------
__global__ __launch_bounds__(256) void attn_mfma_kernel(
    const float* __restrict__ qkv, float* __restrict__ hbuf)
{
    const int tid  = threadIdx.x;
    const int lane = tid & 63;
    const int wv   = tid >> 6;
    const int n16  = lane & 15;
    const int quad = lane >> 4;
    const int qt = blockIdx.x & 31;
    const int hh = (blockIdx.x >> 5) & 15;
    const int bb = blockIdx.x >> 9;
    const int q0 = qt * 64;
    const int w16 = wv * 16;

    __shared__ __bf16 Qs[64][72];
    __shared__ __bf16 Ks[64][72];
    __shared__ __bf16 Vt[64][72];
    __shared__ __bf16 Ps[64][72];

    // ---- stage Q tile (scaled by 1/sqrt(D) = 0.125) ----
    for (int i = tid; i < 1024; i += 256) {
        int r = i >> 4, d4 = (i & 15) * 4;
        float4 q4 = *(const float4*)&qkv[(size_t)(bb * L_ + q0 + r) * 3072 + hh * 64 + d4];
        bf16x4 t;
        t[0] = (__bf16)(q4.x * 0.125f);
        t[1] = (__bf16)(q4.y * 0.125f);
        t[2] = (__bf16)(q4.z * 0.125f);
        t[3] = (__bf16)(q4.w * 0.125f);
        *(bf16x4*)&Qs[r][d4] = t;
    }
    __syncthreads();

    // hoisted Q A-frags (constant across K-tiles)
    const bf16x8 qa0 = *(const bf16x8*)&Qs[w16 + n16][quad * 8];
    const bf16x8 qa1 = *(const bf16x8*)&Qs[w16 + n16][32 + quad * 8];

    f32x4 O0 = {0.f,0.f,0.f,0.f}, O1 = {0.f,0.f,0.f,0.f};
    f32x4 O2 = {0.f,0.f,0.f,0.f}, O3 = {0.f,0.f,0.f,0.f};
    float m_run[4] = {-1e30f, -1e30f, -1e30f, -1e30f};
    float l_run[4] = {0.f, 0.f, 0.f, 0.f};

    for (int j0 = 0; j0 < L_; j0 += 64) {
        // ---- stage K (natural) ----
        for (int i = tid; i < 1024; i += 256) {
            int r = i >> 4, d4 = (i & 15) * 4;
            size_t base = (size_t)(bb * L_ + j0 + r) * 3072 + hh * 64 + d4;
            float4 k4 = *(const float4*)&qkv[base + 1024];
            bf16x4 t;
            t[0] = (__bf16)k4.x; t[1] = (__bf16)k4.y;
            t[2] = (__bf16)k4.z; t[3] = (__bf16)k4.w;
            *(bf16x4*)&Ks[r][d4] = t;
        }
        // ---- stage V transposed: Vt[d][key] ----
        for (int i = tid; i < 512; i += 256) {
            int r2 = (i >> 4) * 2, d4 = (i & 15) * 4;
            size_t base = (size_t)(bb * L_ + j0 + r2) * 3072 + hh * 64 + 2048 + d4;
            float4 v0 = *(const float4*)&qkv[base];
            float4 v1 = *(const float4*)&qkv[base + 3072];
            float a0[4] = {v0.x, v0.y, v0.z, v0.w};
            float a1[4] = {v1.x, v1.y, v1.z, v1.w};
            #pragma unroll
            for (int dd = 0; dd < 4; dd++) {
                bf16x2 t;
                t[0] = (__bf16)a0[dd];
                t[1] = (__bf16)a1[dd];
                *(bf16x2*)&Vt[d4 + dd][r2] = t;
            }
        }
        __syncthreads();

        // ---- S = Q @ K^T (4 key-groups x 2 MFMAs over d) ----
        f32x4 S0 = {0.f,0.f,0.f,0.f}, S1 = {0.f,0.f,0.f,0.f};
        f32x4 S2 = {0.f,0.f,0.f,0.f}, S3 = {0.f,0.f,0.f,0.f};
        {
            bf16x8 b0, b1;
            b0 = *(const bf16x8*)&Ks[ 0 + n16][quad * 8];
            b1 = *(const bf16x8*)&Ks[ 0 + n16][32 + quad * 8];
            S0 = __builtin_amdgcn_mfma_f32_16x16x32_bf16(qa0, b0, S0, 0, 0, 0);
            S0 = __builtin_amdgcn_mfma_f32_16x16x32_bf16(qa1, b1, S0, 0, 0, 0);
            b0 = *(const bf16x8*)&Ks[16 + n16][quad * 8];
            b1 = *(const bf16x8*)&Ks[16 + n16][32 + quad * 8];
            S1 = __builtin_amdgcn_mfma_f32_16x16x32_bf16(qa0, b0, S1, 0, 0, 0);
            S1 = __builtin_amdgcn_mfma_f32_16x16x32_bf16(qa1, b1, S1, 0, 0, 0);
            b0 = *(const bf16x8*)&Ks[32 + n16][quad * 8];
            b1 = *(const bf16x8*)&Ks[32 + n16][32 + quad * 8];
            S2 = __builtin_amdgcn_mfma_f32_16x16x32_bf16(qa0, b0, S2, 0, 0, 0);
            S2 = __builtin_amdgcn_mfma_f32_16x16x32_bf16(qa1, b1, S2, 0, 0, 0);
            b0 = *(const bf16x8*)&Ks[48 + n16][quad * 8];
            b1 = *(const bf16x8*)&Ks[48 + n16][32 + quad * 8];
            S3 = __builtin_amdgcn_mfma_f32_16x16x32_bf16(qa0, b0, S3, 0, 0, 0);
            S3 = __builtin_amdgcn_mfma_f32_16x16x32_bf16(qa1, b1, S3, 0, 0, 0);
        }

        // ---- online softmax (C-layout: reg r -> q-row quad*4+r) ----
        float alpha[4];
        #pragma unroll
        for (int r = 0; r < 4; r++) {
            float rm = fmaxf(fmaxf(S0[r], S1[r]), fmaxf(S2[r], S3[r]));
            #pragma unroll
            for (int msk = 1; msk < 16; msk <<= 1)
                rm = fmaxf(rm, __shfl_xor(rm, msk, 64));
            float m_new = fmaxf(m_run[r], rm);
            alpha[r] = __expf(m_run[r] - m_new);
            m_run[r] = m_new;

            float p0 = __expf(S0[r] - m_new);
            float p1 = __expf(S1[r] - m_new);
            float p2 = __expf(S2[r] - m_new);
            float p3 = __expf(S3[r] - m_new);
            int prow = w16 + quad * 4 + r;
            Ps[prow][ 0 + n16] = (__bf16)p0;
            Ps[prow][16 + n16] = (__bf16)p1;
            Ps[prow][32 + n16] = (__bf16)p2;
            Ps[prow][48 + n16] = (__bf16)p3;
            float ts = p0 + p1 + p2 + p3;
            #pragma unroll
            for (int msk = 1; msk < 16; msk <<= 1)
                ts += __shfl_xor(ts, msk, 64);
            l_run[r] = l_run[r] * alpha[r] + ts;
        }

        // ---- broadcast alpha for q-row = n16 (O^T col) ----
        {
            float a01 = (n16 & 1) ? alpha[1] : alpha[0];
            float a23 = (n16 & 1) ? alpha[3] : alpha[2];
            float sv  = (n16 & 2) ? a23 : a01;
            float al  = __shfl(sv, ((n16 >> 2) << 4) | n16, 64);
            O0 *= al; O1 *= al; O2 *= al; O3 *= al;
        }

        // ---- O^T += V^T @ P^T ----
        {
            bf16x8 pb0 = *(const bf16x8*)&Ps[w16 + n16][quad * 8];
            bf16x8 pb1 = *(const bf16x8*)&Ps[w16 + n16][32 + quad * 8];
            bf16x8 a0, a1;
            a0 = *(const bf16x8*)&Vt[ 0 + n16][quad * 8];
            a1 = *(const bf16x8*)&Vt[ 0 + n16][32 + quad * 8];
            O0 = __builtin_amdgcn_mfma_f32_16x16x32_bf16(a0, pb0, O0, 0, 0, 0);
            O0 = __builtin_amdgcn_mfma_f32_16x16x32_bf16(a1, pb1, O0, 0, 0, 0);
            a0 = *(const bf16x8*)&Vt[16 + n16][quad * 8];
            a1 = *(const bf16x8*)&Vt[16 + n16][32 + quad * 8];
            O1 = __builtin_amdgcn_mfma_f32_16x16x32_bf16(a0, pb0, O1, 0, 0, 0);
            O1 = __builtin_amdgcn_mfma_f32_16x16x32_bf16(a1, pb1, O1, 0, 0, 0);
            a0 = *(const bf16x8*)&Vt[32 + n16][quad * 8];
            a1 = *(const bf16x8*)&Vt[32 + n16][32 + quad * 8];
            O2 = __builtin_amdgcn_mfma_f32_16x16x32_bf16(a0, pb0, O2, 0, 0, 0);
            O2 = __builtin_amdgcn_mfma_f32_16x16x32_bf16(a1, pb1, O2, 0, 0, 0);
            a0 = *(const bf16x8*)&Vt[48 + n16][quad * 8];
            a1 = *(const bf16x8*)&Vt[48 + n16][32 + quad * 8];
            O3 = __builtin_amdgcn_mfma_f32_16x16x32_bf16(a0, pb0, O3, 0, 0, 0);
            O3 = __builtin_amdgcn_mfma_f32_16x16x32_bf16(a1, pb1, O3, 0, 0, 0);
        }
        __syncthreads();
    }

    // ---- epilogue: broadcast 1/l for q-row = n16, float4 stores ----
    float l01 = (n16 & 1) ? l_run[1] : l_run[0];
    float l23 = (n16 & 1) ? l_run[3] : l_run[2];
    float lv  = (n16 & 2) ? l23 : l01;
    float linv = 1.0f / __shfl(lv, ((n16 >> 2) << 4) | n16, 64);

    const size_t orow = (size_t)(bb * L_ + q0 + w16 + n16) * 1024 + hh * 64 + quad * 4;
    {
        float4 o;
        o = make_float4(O0[0]*linv, O0[1]*linv, O0[2]*linv, O0[3]*linv);
        *(float4*)&hbuf[orow +  0] = o;
        o = make_float4(O1[0]*linv, O1[1]*linv, O1[2]*linv, O1[3]*linv);
        *(float4*)&hbuf[orow + 16] = o;
        o = make_float4(O2[0]*linv, O2[1]*linv, O2[2]*linv, O2[3]*linv);
        *(float4*)&hbuf[orow + 32] = o;
        o = make_float4(O3[0]*linv, O3[1]*linv, O3[2]*linv, O3[3]*linv);
        *(float4*)&hbuf[orow + 48] = o;
    }
}

// ---------------------------------------------------------------------------
extern "C" void kernel_launch(void* const* d_in, const int* in_sizes, int n_in,
                              void* d_out, int out_size, void* d_ws, size_t ws_size,
                              hipStream_t stream)
{
    const float* x       = (const float*)d_in[0];
    const float* Wqkv    = (const float*)d_in[1];
    const float* bqkv    = (const float*)d_in[2];
    const float* q_gamma = (const float*)d_in[3];
    const float* k_gamma = (const float*)d_in[4];
    const float* Wout    = (const float*)d_in[5];
    const float* bout    = (const float*)d_in[6];
    float* out = (float*)d_out;

    float* qkv  = (float*)d_ws;                          // 96 MB
    float* hbuf = qkv + (size_t)B_ * L_ * 3 * C_;        // 32 MB

    gemm_bias_kernel<<<dim3(3 * C_ / 128, B_ * L_ / 128), 256, 0, stream>>>(
        x, Wqkv, bqkv, qkv, B_ * L_, 3 * C_, C_);

    rmsnorm_kernel<<<2 * B_ * L_ * H_ / 4, 256, 0, stream>>>(qkv, q_gamma, k_gamma);

    attn_mfma_kernel<<<B_ * H_ * (L_ / 64), 256, 0, stream>>>(qkv, hbuf);

    gemm_bias_kernel<<<dim3(C_ / 128, B_ * L_ / 128), 256, 0, stream>>>(
        hbuf, Wout, bout, out, B_ * L_, C_, C_);
}

// Round 3
// 527.334 us; speedup vs baseline: 4.4803x; 2.2544x over previous
//
#include <hip/hip_runtime.h>
#include <hip/hip_bf16.h>
#include <cstdint>
#include <cstddef>

#define B_ 4
#define L_ 2048
#define C_ 1024
#define H_ 16
#define D_ 64

typedef __bf16    bf16x2 __attribute__((ext_vector_type(2)));
typedef __bf16    bf16x4 __attribute__((ext_vector_type(4)));
typedef __bf16    bf16x8 __attribute__((ext_vector_type(8)));
typedef _Float16  f16x4  __attribute__((ext_vector_type(4)));
typedef _Float16  f16x8  __attribute__((ext_vector_type(8)));
typedef float     f32x4  __attribute__((ext_vector_type(4)));

// async global->LDS, 16 B per lane. LDS dest = wave-uniform base + lane*16.
typedef const __attribute__((address_space(1))) uint32_t* gas_ptr;
typedef __attribute__((address_space(3))) uint32_t* las_ptr;
__device__ __forceinline__ void gl_lds16(const void* g, void* l) {
    __builtin_amdgcn_global_load_lds((gas_ptr)(uintptr_t)g,
                                     (las_ptr)(uintptr_t)l, 16, 0, 0);
}

// ---------------------------------------------------------------------------
// fp32 -> fp16 elementwise (4 elems/thread)
// ---------------------------------------------------------------------------
__global__ __launch_bounds__(256) void cvt_f16_kernel(
    const float* __restrict__ in, _Float16* __restrict__ out)
{
    int i = (blockIdx.x * 256 + threadIdx.x) * 4;
    float4 v = *(const float4*)&in[i];
    f16x4 o = {(_Float16)v.x, (_Float16)v.y, (_Float16)v.z, (_Float16)v.w};
    *(f16x4*)&out[i] = o;
}

// ---------------------------------------------------------------------------
// W [K][N] fp32 -> Wt [N][K] fp16 (LDS-tiled transpose, 64x64 tile)
// ---------------------------------------------------------------------------
__global__ __launch_bounds__(256) void tr_cvt_f16_kernel(
    const float* __restrict__ W, _Float16* __restrict__ Wt, int K, int N)
{
    __shared__ float tile[64][65];
    const int tid = threadIdx.x;
    const int k0 = blockIdx.y * 64, n0 = blockIdx.x * 64;
    for (int i = tid; i < 1024; i += 256) {
        int r = i >> 4, c4 = (i & 15) * 4;
        float4 v = *(const float4*)&W[(size_t)(k0 + r) * N + n0 + c4];
        tile[r][c4 + 0] = v.x; tile[r][c4 + 1] = v.y;
        tile[r][c4 + 2] = v.z; tile[r][c4 + 3] = v.w;
    }
    __syncthreads();
    for (int i = tid; i < 1024; i += 256) {
        int n = i >> 4, k4 = (i & 15) * 4;
        f16x4 o = {(_Float16)tile[k4 + 0][n], (_Float16)tile[k4 + 1][n],
                   (_Float16)tile[k4 + 2][n], (_Float16)tile[k4 + 3][n]};
        *(f16x4*)&Wt[(size_t)(n0 + n) * K + k0 + k4] = o;
    }
}

// ---------------------------------------------------------------------------
// fp16 MFMA GEMM: C = A(MxK) @ Bt^T + bias, A[M][K], Bt[N][K] (both fp16,
// K-contiguous). 128x128 tile, BK=32, 256 thr = 4 waves (2x2, 64x64/wave,
// 4x4 grid of 16x16x32 MFMAs). Staging via global_load_lds width=16 (m97).
// OUT_BF16=1 -> stores __bf16, else fp32.
// ---------------------------------------------------------------------------
template <int OUT_BF16>
__global__ __launch_bounds__(256) void gemm_f16_bt_kernel(
    const _Float16* __restrict__ A, const _Float16* __restrict__ Bt,
    const float* __restrict__ bias, void* __restrict__ Cout,
    int M, int N, int K)
{
    __shared__ __align__(16) _Float16 Ash[128 * 32];
    __shared__ __align__(16) _Float16 Bsh[128 * 32];

    const int tid  = threadIdx.x;
    const int lane = tid & 63;
    const int wv   = tid >> 6;       // 0..3
    const int wm   = wv & 1, wn = wv >> 1;
    const int n16  = lane & 15, quad = lane >> 4;
    const int brow = blockIdx.y * 128;
    const int bcol = blockIdx.x * 128;

    // staging: wave wv covers rows wv*32..+31 of each 128x32 tile,
    // lane -> (row = lane>>2, col8 = (lane&3)*8); LDS offset == lane*16 B.
    const int srow = lane >> 2;
    const int scol = (lane & 3) * 8;
    const _Float16* gA = A  + (size_t)(brow + wv * 32 + srow) * K + scol;
    const _Float16* gB = Bt + (size_t)(bcol + wv * 32 + srow) * K + scol;
    _Float16* lA0 = &Ash[wv * 1024];
    _Float16* lA1 = &Ash[wv * 1024 + 512];
    _Float16* lB0 = &Bsh[wv * 1024];
    _Float16* lB1 = &Bsh[wv * 1024 + 512];

    f32x4 acc[4][4] = {};

    for (int k0 = 0; k0 < K; k0 += 32) {
        gl_lds16(gA + k0,            lA0);
        gl_lds16(gA + k0 + 16 * (size_t)K, lA1);
        gl_lds16(gB + k0,            lB0);
        gl_lds16(gB + k0 + 16 * (size_t)K, lB1);
        __syncthreads();

        f16x8 ar[4], br[4];
        #pragma unroll
        for (int t = 0; t < 4; t++) {
            ar[t] = *(const f16x8*)&Ash[(wm * 64 + t * 16 + n16) * 32 + quad * 8];
            br[t] = *(const f16x8*)&Bsh[(wn * 64 + t * 16 + n16) * 32 + quad * 8];
        }
        #pragma unroll
        for (int i = 0; i < 4; i++)
            #pragma unroll
            for (int j = 0; j < 4; j++)
                acc[i][j] = __builtin_amdgcn_mfma_f32_16x16x32_f16(
                    ar[i], br[j], acc[i][j], 0, 0, 0);
        __syncthreads();
    }

    // epilogue: C-layout col = n16 (n), row = quad*4+reg (m)
    #pragma unroll
    for (int j = 0; j < 4; j++) {
        const int col = bcol + wn * 64 + j * 16 + n16;
        const float bv = bias[col];
        #pragma unroll
        for (int i = 0; i < 4; i++) {
            const int row0 = brow + wm * 64 + i * 16 + quad * 4;
            #pragma unroll
            for (int r = 0; r < 4; r++) {
                float v = acc[i][j][r] + bv;
                if (OUT_BF16)
                    ((__bf16*)Cout)[(size_t)(row0 + r) * N + col] = (__bf16)v;
                else
                    ((float*)Cout)[(size_t)(row0 + r) * N + col] = v;
            }
        }
    }
}

// ---------------------------------------------------------------------------
// Per-head RMS norm of q and k rows, in place on bf16 qkv.
// Folds the attention scale 1/sqrt(D) into q: q *= gamma (no *8),
// k *= gamma * 8.
// ---------------------------------------------------------------------------
__global__ __launch_bounds__(256) void rmsnorm_bf16_kernel(
    __bf16* __restrict__ qkv, const float* __restrict__ q_gamma,
    const float* __restrict__ k_gamma)
{
    const int lane = threadIdx.x & 63;
    const int wid = blockIdx.x * 4 + (threadIdx.x >> 6);
    const int NROWS = B_ * L_ * H_;
    int s, row;
    const float* gamma;
    float scl;
    if (wid < NROWS) { s = 0; row = wid;         gamma = q_gamma; scl = 1.0f; }
    else             { s = 1; row = wid - NROWS; gamma = k_gamma; scl = 8.0f; }
    const int h  = row & 15;
    const int bl = row >> 4;
    const size_t idx = ((size_t)bl * 3 + s) * 1024 + h * 64 + lane;
    float v = (float)qkv[idx];
    float ss = v * v;
    #pragma unroll
    for (int m = 1; m < 64; m <<= 1) ss += __shfl_xor(ss, m, 64);
    float denom = fmaxf(sqrtf(ss), 1e-12f);
    qkv[idx] = (__bf16)((v / denom) * gamma[h * 64 + lane] * scl);
}

// ---------------------------------------------------------------------------
// MFMA flash attention, bf16 qkv input (q pre-scaled by 1/sqrt(D) in rmsnorm),
// fp16 output h16. Structure identical to R2 (verified), staging now bf16.
// ---------------------------------------------------------------------------
__global__ __launch_bounds__(256) void attn_mfma_kernel(
    const __bf16* __restrict__ qkv, _Float16* __restrict__ h16)
{
    const int tid  = threadIdx.x;
    const int lane = tid & 63;
    const int wv   = tid >> 6;
    const int n16  = lane & 15;
    const int quad = lane >> 4;
    const int qt = blockIdx.x & 31;
    const int hh = (blockIdx.x >> 5) & 15;
    const int bb = blockIdx.x >> 9;
    const int q0 = qt * 64;
    const int w16 = wv * 16;

    __shared__ __align__(16) __bf16 Qs[64][72];
    __shared__ __align__(16) __bf16 Ks[64][72];
    __shared__ __align__(16) __bf16 Vt[64][72];
    __shared__ __align__(16) __bf16 Ps[64][72];

    // ---- stage Q tile (already scaled in rmsnorm) ----
    for (int i = tid; i < 512; i += 256) {
        int r = i >> 3, d8 = (i & 7) * 8;
        *(bf16x8*)&Qs[r][d8] =
            *(const bf16x8*)&qkv[(size_t)(bb * L_ + q0 + r) * 3072 + hh * 64 + d8];
    }
    __syncthreads();

    const bf16x8 qa0 = *(const bf16x8*)&Qs[w16 + n16][quad * 8];
    const bf16x8 qa1 = *(const bf16x8*)&Qs[w16 + n16][32 + quad * 8];

    f32x4 O0 = {0.f,0.f,0.f,0.f}, O1 = {0.f,0.f,0.f,0.f};
    f32x4 O2 = {0.f,0.f,0.f,0.f}, O3 = {0.f,0.f,0.f,0.f};
    float m_run[4] = {-1e30f, -1e30f, -1e30f, -1e30f};
    float l_run[4] = {0.f, 0.f, 0.f, 0.f};

    for (int j0 = 0; j0 < L_; j0 += 64) {
        // ---- stage K ----
        for (int i = tid; i < 512; i += 256) {
            int r = i >> 3, d8 = (i & 7) * 8;
            *(bf16x8*)&Ks[r][d8] =
                *(const bf16x8*)&qkv[(size_t)(bb * L_ + j0 + r) * 3072 + 1024 + hh * 64 + d8];
        }
        // ---- stage V transposed: Vt[d][key] ----
        for (int i = tid; i < 512; i += 256) {
            int r2 = (i >> 4) * 2, d4 = (i & 15) * 4;
            const __bf16* p0 = &qkv[(size_t)(bb * L_ + j0 + r2) * 3072 + 2048 + hh * 64 + d4];
            bf16x4 v0 = *(const bf16x4*)p0;
            bf16x4 v1 = *(const bf16x4*)(p0 + 3072);
            #pragma unroll
            for (int dd = 0; dd < 4; dd++) {
                bf16x2 t;
                t[0] = v0[dd];
                t[1] = v1[dd];
                *(bf16x2*)&Vt[d4 + dd][r2] = t;
            }
        }
        __syncthreads();

        // ---- S = Q @ K^T ----
        f32x4 S0 = {0.f,0.f,0.f,0.f}, S1 = {0.f,0.f,0.f,0.f};
        f32x4 S2 = {0.f,0.f,0.f,0.f}, S3 = {0.f,0.f,0.f,0.f};
        {
            bf16x8 b0, b1;
            b0 = *(const bf16x8*)&Ks[ 0 + n16][quad * 8];
            b1 = *(const bf16x8*)&Ks[ 0 + n16][32 + quad * 8];
            S0 = __builtin_amdgcn_mfma_f32_16x16x32_bf16(qa0, b0, S0, 0, 0, 0);
            S0 = __builtin_amdgcn_mfma_f32_16x16x32_bf16(qa1, b1, S0, 0, 0, 0);
            b0 = *(const bf16x8*)&Ks[16 + n16][quad * 8];
            b1 = *(const bf16x8*)&Ks[16 + n16][32 + quad * 8];
            S1 = __builtin_amdgcn_mfma_f32_16x16x32_bf16(qa0, b0, S1, 0, 0, 0);
            S1 = __builtin_amdgcn_mfma_f32_16x16x32_bf16(qa1, b1, S1, 0, 0, 0);
            b0 = *(const bf16x8*)&Ks[32 + n16][quad * 8];
            b1 = *(const bf16x8*)&Ks[32 + n16][32 + quad * 8];
            S2 = __builtin_amdgcn_mfma_f32_16x16x32_bf16(qa0, b0, S2, 0, 0, 0);
            S2 = __builtin_amdgcn_mfma_f32_16x16x32_bf16(qa1, b1, S2, 0, 0, 0);
            b0 = *(const bf16x8*)&Ks[48 + n16][quad * 8];
            b1 = *(const bf16x8*)&Ks[48 + n16][32 + quad * 8];
            S3 = __builtin_amdgcn_mfma_f32_16x16x32_bf16(qa0, b0, S3, 0, 0, 0);
            S3 = __builtin_amdgcn_mfma_f32_16x16x32_bf16(qa1, b1, S3, 0, 0, 0);
        }

        // ---- online softmax ----
        float alpha[4];
        #pragma unroll
        for (int r = 0; r < 4; r++) {
            float rm = fmaxf(fmaxf(S0[r], S1[r]), fmaxf(S2[r], S3[r]));
            #pragma unroll
            for (int msk = 1; msk < 16; msk <<= 1)
                rm = fmaxf(rm, __shfl_xor(rm, msk, 64));
            float m_new = fmaxf(m_run[r], rm);
            alpha[r] = __expf(m_run[r] - m_new);
            m_run[r] = m_new;

            float p0 = __expf(S0[r] - m_new);
            float p1 = __expf(S1[r] - m_new);
            float p2 = __expf(S2[r] - m_new);
            float p3 = __expf(S3[r] - m_new);
            int prow = w16 + quad * 4 + r;
            Ps[prow][ 0 + n16] = (__bf16)p0;
            Ps[prow][16 + n16] = (__bf16)p1;
            Ps[prow][32 + n16] = (__bf16)p2;
            Ps[prow][48 + n16] = (__bf16)p3;
            float ts = p0 + p1 + p2 + p3;
            #pragma unroll
            for (int msk = 1; msk < 16; msk <<= 1)
                ts += __shfl_xor(ts, msk, 64);
            l_run[r] = l_run[r] * alpha[r] + ts;
        }

        // ---- rescale O by alpha (col = q-row = n16) ----
        {
            float a01 = (n16 & 1) ? alpha[1] : alpha[0];
            float a23 = (n16 & 1) ? alpha[3] : alpha[2];
            float sv  = (n16 & 2) ? a23 : a01;
            float al  = __shfl(sv, ((n16 >> 2) << 4) | n16, 64);
            O0 *= al; O1 *= al; O2 *= al; O3 *= al;
        }

        // ---- O^T += V^T @ P^T ----
        {
            bf16x8 pb0 = *(const bf16x8*)&Ps[w16 + n16][quad * 8];
            bf16x8 pb1 = *(const bf16x8*)&Ps[w16 + n16][32 + quad * 8];
            bf16x8 a0, a1;
            a0 = *(const bf16x8*)&Vt[ 0 + n16][quad * 8];
            a1 = *(const bf16x8*)&Vt[ 0 + n16][32 + quad * 8];
            O0 = __builtin_amdgcn_mfma_f32_16x16x32_bf16(a0, pb0, O0, 0, 0, 0);
            O0 = __builtin_amdgcn_mfma_f32_16x16x32_bf16(a1, pb1, O0, 0, 0, 0);
            a0 = *(const bf16x8*)&Vt[16 + n16][quad * 8];
            a1 = *(const bf16x8*)&Vt[16 + n16][32 + quad * 8];
            O1 = __builtin_amdgcn_mfma_f32_16x16x32_bf16(a0, pb0, O1, 0, 0, 0);
            O1 = __builtin_amdgcn_mfma_f32_16x16x32_bf16(a1, pb1, O1, 0, 0, 0);
            a0 = *(const bf16x8*)&Vt[32 + n16][quad * 8];
            a1 = *(const bf16x8*)&Vt[32 + n16][32 + quad * 8];
            O2 = __builtin_amdgcn_mfma_f32_16x16x32_bf16(a0, pb0, O2, 0, 0, 0);
            O2 = __builtin_amdgcn_mfma_f32_16x16x32_bf16(a1, pb1, O2, 0, 0, 0);
            a0 = *(const bf16x8*)&Vt[48 + n16][quad * 8];
            a1 = *(const bf16x8*)&Vt[48 + n16][32 + quad * 8];
            O3 = __builtin_amdgcn_mfma_f32_16x16x32_bf16(a0, pb0, O3, 0, 0, 0);
            O3 = __builtin_amdgcn_mfma_f32_16x16x32_bf16(a1, pb1, O3, 0, 0, 0);
        }
        __syncthreads();
    }

    // ---- epilogue: divide by l, write fp16 h ----
    float l01 = (n16 & 1) ? l_run[1] : l_run[0];
    float l23 = (n16 & 1) ? l_run[3] : l_run[2];
    float lv  = (n16 & 2) ? l23 : l01;
    float linv = 1.0f / __shfl(lv, ((n16 >> 2) << 4) | n16, 64);

    const size_t orow = (size_t)(bb * L_ + q0 + w16 + n16) * 1024 + hh * 64 + quad * 4;
    {
        f16x4 o;
        o = (f16x4){(_Float16)(O0[0]*linv), (_Float16)(O0[1]*linv),
                    (_Float16)(O0[2]*linv), (_Float16)(O0[3]*linv)};
        *(f16x4*)&h16[orow +  0] = o;
        o = (f16x4){(_Float16)(O1[0]*linv), (_Float16)(O1[1]*linv),
                    (_Float16)(O1[2]*linv), (_Float16)(O1[3]*linv)};
        *(f16x4*)&h16[orow + 16] = o;
        o = (f16x4){(_Float16)(O2[0]*linv), (_Float16)(O2[1]*linv),
                    (_Float16)(O2[2]*linv), (_Float16)(O2[3]*linv)};
        *(f16x4*)&h16[orow + 32] = o;
        o = (f16x4){(_Float16)(O3[0]*linv), (_Float16)(O3[1]*linv),
                    (_Float16)(O3[2]*linv), (_Float16)(O3[3]*linv)};
        *(f16x4*)&h16[orow + 48] = o;
    }
}

// ---------------------------------------------------------------------------
extern "C" void kernel_launch(void* const* d_in, const int* in_sizes, int n_in,
                              void* d_out, int out_size, void* d_ws, size_t ws_size,
                              hipStream_t stream)
{
    const float* x       = (const float*)d_in[0];
    const float* Wqkv    = (const float*)d_in[1];
    const float* bqkv    = (const float*)d_in[2];
    const float* q_gamma = (const float*)d_in[3];
    const float* k_gamma = (const float*)d_in[4];
    const float* Wout    = (const float*)d_in[5];
    const float* bout    = (const float*)d_in[6];
    float* out = (float*)d_out;

    uint8_t* ws = (uint8_t*)d_ws;
    _Float16* x16   = (_Float16*)(ws);                      // 16 MB
    _Float16* Wq16  = (_Float16*)(ws + (16ull << 20));      //  6 MB
    _Float16* Wo16  = (_Float16*)(ws + (22ull << 20));      //  2 MB
    __bf16*   qkv16 = (__bf16*)  (ws + (24ull << 20));      // 48 MB
    _Float16* h16   = (_Float16*)(ws + (72ull << 20));      // 16 MB (total 88)

    // 1) convert x -> fp16; transpose+convert weights -> [N][K] fp16
    cvt_f16_kernel<<<(B_ * L_ * C_) / 1024, 256, 0, stream>>>(x, x16);
    tr_cvt_f16_kernel<<<dim3(3 * C_ / 64, C_ / 64), 256, 0, stream>>>(Wqkv, Wq16, C_, 3 * C_);
    tr_cvt_f16_kernel<<<dim3(C_ / 64, C_ / 64), 256, 0, stream>>>(Wout, Wo16, C_, C_);

    // 2) qkv = x @ Wqkv + bqkv  -> bf16   (M=8192, N=3072, K=1024)
    gemm_f16_bt_kernel<1><<<dim3(3 * C_ / 128, B_ * L_ / 128), 256, 0, stream>>>(
        x16, Wq16, bqkv, qkv16, B_ * L_, 3 * C_, C_);

    // 3) RMS-norm q,k in place (scale folded into q)
    rmsnorm_bf16_kernel<<<2 * B_ * L_ * H_ / 4, 256, 0, stream>>>(qkv16, q_gamma, k_gamma);

    // 4) flash attention -> h16
    attn_mfma_kernel<<<B_ * H_ * (L_ / 64), 256, 0, stream>>>(qkv16, h16);

    // 5) out = h @ Wout + bout  -> fp32   (M=8192, N=1024, K=1024)
    gemm_f16_bt_kernel<0><<<dim3(C_ / 128, B_ * L_ / 128), 256, 0, stream>>>(
        h16, Wo16, bout, out, B_ * L_, C_, C_);
}

// Round 4
// 426.905 us; speedup vs baseline: 5.5343x; 1.2352x over previous
//
#include <hip/hip_runtime.h>
#include <hip/hip_bf16.h>
#include <cstdint>
#include <cstddef>

#define B_ 4
#define L_ 2048
#define C_ 1024
#define H_ 16
#define D_ 64

typedef __bf16    bf16x2 __attribute__((ext_vector_type(2)));
typedef __bf16    bf16x4 __attribute__((ext_vector_type(4)));
typedef __bf16    bf16x8 __attribute__((ext_vector_type(8)));
typedef _Float16  f16x4  __attribute__((ext_vector_type(4)));
typedef _Float16  f16x8  __attribute__((ext_vector_type(8)));
typedef float     f32x4  __attribute__((ext_vector_type(4)));

// async global->LDS, 16 B per lane. LDS dest = wave-uniform base + lane*16.
typedef const __attribute__((address_space(1))) uint32_t* gas_ptr;
typedef __attribute__((address_space(3))) uint32_t* las_ptr;
__device__ __forceinline__ void gl_lds16(const void* g, void* l) {
    __builtin_amdgcn_global_load_lds((gas_ptr)(uintptr_t)g,
                                     (las_ptr)(uintptr_t)l, 16, 0, 0);
}

// ---------------------------------------------------------------------------
// fp32 -> fp16 elementwise (4 elems/thread)
// ---------------------------------------------------------------------------
__global__ __launch_bounds__(256) void cvt_f16_kernel(
    const float* __restrict__ in, _Float16* __restrict__ out)
{
    int i = (blockIdx.x * 256 + threadIdx.x) * 4;
    float4 v = *(const float4*)&in[i];
    f16x4 o = {(_Float16)v.x, (_Float16)v.y, (_Float16)v.z, (_Float16)v.w};
    *(f16x4*)&out[i] = o;
}

// ---------------------------------------------------------------------------
// W [K][N] fp32 -> Wt [N][K] fp16 (LDS-tiled transpose, 64x64 tile)
// ---------------------------------------------------------------------------
__global__ __launch_bounds__(256) void tr_cvt_f16_kernel(
    const float* __restrict__ W, _Float16* __restrict__ Wt, int K, int N)
{
    __shared__ float tile[64][65];
    const int tid = threadIdx.x;
    const int k0 = blockIdx.y * 64, n0 = blockIdx.x * 64;
    for (int i = tid; i < 1024; i += 256) {
        int r = i >> 4, c4 = (i & 15) * 4;
        float4 v = *(const float4*)&W[(size_t)(k0 + r) * N + n0 + c4];
        tile[r][c4 + 0] = v.x; tile[r][c4 + 1] = v.y;
        tile[r][c4 + 2] = v.z; tile[r][c4 + 3] = v.w;
    }
    __syncthreads();
    for (int i = tid; i < 1024; i += 256) {
        int n = i >> 4, k4 = (i & 15) * 4;
        f16x4 o = {(_Float16)tile[k4 + 0][n], (_Float16)tile[k4 + 1][n],
                   (_Float16)tile[k4 + 2][n], (_Float16)tile[k4 + 3][n]};
        *(f16x4*)&Wt[(size_t)(n0 + n) * K + k0 + k4] = o;
    }
}

// ---------------------------------------------------------------------------
// fp16 MFMA GEMM (m97 structure) — unchanged from R3.
// ---------------------------------------------------------------------------
template <int OUT_BF16>
__global__ __launch_bounds__(256) void gemm_f16_bt_kernel(
    const _Float16* __restrict__ A, const _Float16* __restrict__ Bt,
    const float* __restrict__ bias, void* __restrict__ Cout,
    int M, int N, int K)
{
    __shared__ __align__(16) _Float16 Ash[128 * 32];
    __shared__ __align__(16) _Float16 Bsh[128 * 32];

    const int tid  = threadIdx.x;
    const int lane = tid & 63;
    const int wv   = tid >> 6;
    const int wm   = wv & 1, wn = wv >> 1;
    const int n16  = lane & 15, quad = lane >> 4;
    const int brow = blockIdx.y * 128;
    const int bcol = blockIdx.x * 128;

    const int srow = lane >> 2;
    const int scol = (lane & 3) * 8;
    const _Float16* gA = A  + (size_t)(brow + wv * 32 + srow) * K + scol;
    const _Float16* gB = Bt + (size_t)(bcol + wv * 32 + srow) * K + scol;
    _Float16* lA0 = &Ash[wv * 1024];
    _Float16* lA1 = &Ash[wv * 1024 + 512];
    _Float16* lB0 = &Bsh[wv * 1024];
    _Float16* lB1 = &Bsh[wv * 1024 + 512];

    f32x4 acc[4][4] = {};

    for (int k0 = 0; k0 < K; k0 += 32) {
        gl_lds16(gA + k0,                  lA0);
        gl_lds16(gA + k0 + 16 * (size_t)K, lA1);
        gl_lds16(gB + k0,                  lB0);
        gl_lds16(gB + k0 + 16 * (size_t)K, lB1);
        __syncthreads();

        f16x8 ar[4], br[4];
        #pragma unroll
        for (int t = 0; t < 4; t++) {
            ar[t] = *(const f16x8*)&Ash[(wm * 64 + t * 16 + n16) * 32 + quad * 8];
            br[t] = *(const f16x8*)&Bsh[(wn * 64 + t * 16 + n16) * 32 + quad * 8];
        }
        #pragma unroll
        for (int i = 0; i < 4; i++)
            #pragma unroll
            for (int j = 0; j < 4; j++)
                acc[i][j] = __builtin_amdgcn_mfma_f32_16x16x32_f16(
                    ar[i], br[j], acc[i][j], 0, 0, 0);
        __syncthreads();
    }

    #pragma unroll
    for (int j = 0; j < 4; j++) {
        const int col = bcol + wn * 64 + j * 16 + n16;
        const float bv = bias[col];
        #pragma unroll
        for (int i = 0; i < 4; i++) {
            const int row0 = brow + wm * 64 + i * 16 + quad * 4;
            #pragma unroll
            for (int r = 0; r < 4; r++) {
                float v = acc[i][j][r] + bv;
                if (OUT_BF16)
                    ((__bf16*)Cout)[(size_t)(row0 + r) * N + col] = (__bf16)v;
                else
                    ((float*)Cout)[(size_t)(row0 + r) * N + col] = v;
            }
        }
    }
}

// ---------------------------------------------------------------------------
// Per-head RMS norm of q and k rows, in place on bf16 qkv.
// q scale folds 1/sqrt(D)*8 (=1) AND log2(e) for base-2 softmax;
// k scale = 8 (=sqrt(D)).
// ---------------------------------------------------------------------------
__global__ __launch_bounds__(256) void rmsnorm_bf16_kernel(
    __bf16* __restrict__ qkv, const float* __restrict__ q_gamma,
    const float* __restrict__ k_gamma)
{
    const int lane = threadIdx.x & 63;
    const int wid = blockIdx.x * 4 + (threadIdx.x >> 6);
    const int NROWS = B_ * L_ * H_;
    int s, row;
    const float* gamma;
    float scl;
    if (wid < NROWS) { s = 0; row = wid;         gamma = q_gamma; scl = 1.44269504f; }
    else             { s = 1; row = wid - NROWS; gamma = k_gamma; scl = 8.0f; }
    const int h  = row & 15;
    const int bl = row >> 4;
    const size_t idx = ((size_t)bl * 3 + s) * 1024 + h * 64 + lane;
    float v = (float)qkv[idx];
    float ss = v * v;
    #pragma unroll
    for (int m = 1; m < 64; m <<= 1) ss += __shfl_xor(ss, m, 64);
    float denom = fmaxf(sqrtf(ss), 1e-12f);
    qkv[idx] = (__bf16)((v / denom) * gamma[h * 64 + lane] * scl);
}

// ---------------------------------------------------------------------------
// V pre-transpose: qkv v-part [b][l][h][d] -> vT[b][h][d][l] (bf16).
// Done ONCE globally instead of per q-tile block (32x redundancy removed).
// ---------------------------------------------------------------------------
__global__ __launch_bounds__(256) void tr_v_kernel(
    const __bf16* __restrict__ qkv, __bf16* __restrict__ vT)
{
    __shared__ __bf16 t[64][72];
    const int tid = threadIdx.x;
    const int t0 = blockIdx.x * 64;
    const int bh = blockIdx.y;            // b*16+h
    const int b = bh >> 4, h = bh & 15;
    // coalesced read: token-major rows
    for (int i = tid; i < 512; i += 256) {
        int r = i >> 3, d8 = (i & 7) * 8;
        *(bf16x8*)&t[r][d8] =
            *(const bf16x8*)&qkv[(size_t)(b * L_ + t0 + r) * 3072 + 2048 + h * 64 + d8];
    }
    __syncthreads();
    // transposed write: lane d = i&63 spans all banks (2-way free scalar reads)
    for (int i = tid; i < 512; i += 256) {
        int d = i & 63, k8 = (i >> 6) * 8;
        bf16x8 o;
        #pragma unroll
        for (int j = 0; j < 8; j++) o[j] = t[k8 + j][d];
        *(bf16x8*)&vT[((size_t)bh * 64 + d) * 2048 + t0 + k8] = o;
    }
}

// ---------------------------------------------------------------------------
// MFMA flash attention, S^T formulation.
// Block = (b, h, 64-row q-tile), 4 waves, wave w owns q-rows w*16..+15.
//
// S^T = K @ Q^T via mfma(A=K-rows frag, B=Q-rows frag):
//   C-layout: col = n16 = q-row, row = quad*4+reg = key (per 16-key group g)
//   -> each lane holds 16 keys of ONE q-row: row-max/sum are 15 in-lane VALU
//      ops + 2 shuffles (xor 16, 32). m/l/alpha are per-lane scalars.
// P written packed (4x ds_write_b64, 2-way-free banks), read back as B-frag.
// O^T = V^T @ P^T via A=Vt-rows (staged from precomputed vT, no in-loop
// transpose). O^T col = n16 = q-row -> alpha rescale needs no broadcast.
// Softmax in base 2 (log2e folded into q in rmsnorm): native v_exp_f32.
// ---------------------------------------------------------------------------
__global__ __launch_bounds__(256) void attn_mfma_kernel(
    const __bf16* __restrict__ qkv, const __bf16* __restrict__ vT,
    _Float16* __restrict__ h16)
{
    const int tid  = threadIdx.x;
    const int lane = tid & 63;
    const int wv   = tid >> 6;
    const int n16  = lane & 15;
    const int quad = lane >> 4;
    const int qt = blockIdx.x & 31;
    const int hh = (blockIdx.x >> 5) & 15;
    const int bb = blockIdx.x >> 9;
    const int q0 = qt * 64;
    const int w16 = wv * 16;
    const int bh = bb * 16 + hh;

    __shared__ __align__(16) __bf16 Qs[64][72];
    __shared__ __align__(16) __bf16 Ks[64][72];
    __shared__ __align__(16) __bf16 Vt[64][72];
    __shared__ __align__(16) __bf16 Ps[64][72];

    // ---- stage Q tile (pre-scaled by log2e in rmsnorm) ----
    for (int i = tid; i < 512; i += 256) {
        int r = i >> 3, d8 = (i & 7) * 8;
        *(bf16x8*)&Qs[r][d8] =
            *(const bf16x8*)&qkv[(size_t)(bb * L_ + q0 + r) * 3072 + hh * 64 + d8];
    }
    __syncthreads();

    // hoisted Q B-frags (constant across K-tiles)
    const bf16x8 qb0 = *(const bf16x8*)&Qs[w16 + n16][quad * 8];
    const bf16x8 qb1 = *(const bf16x8*)&Qs[w16 + n16][32 + quad * 8];

    f32x4 O0 = {0.f,0.f,0.f,0.f}, O1 = {0.f,0.f,0.f,0.f};
    f32x4 O2 = {0.f,0.f,0.f,0.f}, O3 = {0.f,0.f,0.f,0.f};
    float m_run = -1e30f, l_run = 0.f;

    for (int j0 = 0; j0 < L_; j0 += 64) {
        // ---- stage K rows ----
        for (int i = tid; i < 512; i += 256) {
            int r = i >> 3, d8 = (i & 7) * 8;
            *(bf16x8*)&Ks[r][d8] =
                *(const bf16x8*)&qkv[(size_t)(bb * L_ + j0 + r) * 3072 + 1024 + hh * 64 + d8];
        }
        // ---- stage Vt rows from precomputed vT (coalesced, no transpose) ----
        for (int i = tid; i < 512; i += 256) {
            int d = i >> 3, k8 = (i & 7) * 8;
            *(bf16x8*)&Vt[d][k8] =
                *(const bf16x8*)&vT[((size_t)bh * 64 + d) * 2048 + j0 + k8];
        }
        __syncthreads();

        // ---- S^T = K @ Q^T : St[g][r] = S^T[key=g*16+quad*4+r][q=w16+n16]
        f32x4 St0 = {0.f,0.f,0.f,0.f}, St1 = {0.f,0.f,0.f,0.f};
        f32x4 St2 = {0.f,0.f,0.f,0.f}, St3 = {0.f,0.f,0.f,0.f};
        {
            bf16x8 a0, a1;
            a0 = *(const bf16x8*)&Ks[ 0 + n16][quad * 8];
            a1 = *(const bf16x8*)&Ks[ 0 + n16][32 + quad * 8];
            St0 = __builtin_amdgcn_mfma_f32_16x16x32_bf16(a0, qb0, St0, 0, 0, 0);
            St0 = __builtin_amdgcn_mfma_f32_16x16x32_bf16(a1, qb1, St0, 0, 0, 0);
            a0 = *(const bf16x8*)&Ks[16 + n16][quad * 8];
            a1 = *(const bf16x8*)&Ks[16 + n16][32 + quad * 8];
            St1 = __builtin_amdgcn_mfma_f32_16x16x32_bf16(a0, qb0, St1, 0, 0, 0);
            St1 = __builtin_amdgcn_mfma_f32_16x16x32_bf16(a1, qb1, St1, 0, 0, 0);
            a0 = *(const bf16x8*)&Ks[32 + n16][quad * 8];
            a1 = *(const bf16x8*)&Ks[32 + n16][32 + quad * 8];
            St2 = __builtin_amdgcn_mfma_f32_16x16x32_bf16(a0, qb0, St2, 0, 0, 0);
            St2 = __builtin_amdgcn_mfma_f32_16x16x32_bf16(a1, qb1, St2, 0, 0, 0);
            a0 = *(const bf16x8*)&Ks[48 + n16][quad * 8];
            a1 = *(const bf16x8*)&Ks[48 + n16][32 + quad * 8];
            St3 = __builtin_amdgcn_mfma_f32_16x16x32_bf16(a0, qb0, St3, 0, 0, 0);
            St3 = __builtin_amdgcn_mfma_f32_16x16x32_bf16(a1, qb1, St3, 0, 0, 0);
        }

        // ---- online softmax: all per-lane, 4 shuffles total ----
        float mt = fmaxf(fmaxf(fmaxf(St0[0], St0[1]), fmaxf(St0[2], St0[3])),
                         fmaxf(fmaxf(St1[0], St1[1]), fmaxf(St1[2], St1[3])));
        mt = fmaxf(mt, fmaxf(fmaxf(fmaxf(St2[0], St2[1]), fmaxf(St2[2], St2[3])),
                             fmaxf(fmaxf(St3[0], St3[1]), fmaxf(St3[2], St3[3]))));
        mt = fmaxf(mt, __shfl_xor(mt, 16, 64));
        mt = fmaxf(mt, __shfl_xor(mt, 32, 64));
        const float m_new = fmaxf(m_run, mt);
        const float alpha = __builtin_amdgcn_exp2f(m_run - m_new);
        m_run = m_new;

        float p[16];
        #pragma unroll
        for (int r = 0; r < 4; r++) {
            p[ 0 + r] = __builtin_amdgcn_exp2f(St0[r] - m_new);
            p[ 4 + r] = __builtin_amdgcn_exp2f(St1[r] - m_new);
            p[ 8 + r] = __builtin_amdgcn_exp2f(St2[r] - m_new);
            p[12 + r] = __builtin_amdgcn_exp2f(St3[r] - m_new);
        }
        float ts = 0.f;
        #pragma unroll
        for (int t = 0; t < 16; t++) ts += p[t];
        ts += __shfl_xor(ts, 16, 64);
        ts += __shfl_xor(ts, 32, 64);
        l_run = l_run * alpha + ts;

        // ---- write P packed: Ps[q=w16+n16][key], 4x b64, wave-private ----
        #pragma unroll
        for (int g = 0; g < 4; g++) {
            bf16x4 t4 = {(__bf16)p[g*4+0], (__bf16)p[g*4+1],
                         (__bf16)p[g*4+2], (__bf16)p[g*4+3]};
            *(bf16x4*)&Ps[w16 + n16][g * 16 + quad * 4] = t4;
        }

        // ---- rescale O (per-lane alpha, col = n16 = q-row) ----
        O0 *= alpha; O1 *= alpha; O2 *= alpha; O3 *= alpha;

        // ---- O^T += V^T @ P^T ----
        {
            bf16x8 pb0 = *(const bf16x8*)&Ps[w16 + n16][quad * 8];
            bf16x8 pb1 = *(const bf16x8*)&Ps[w16 + n16][32 + quad * 8];
            bf16x8 a0, a1;
            a0 = *(const bf16x8*)&Vt[ 0 + n16][quad * 8];
            a1 = *(const bf16x8*)&Vt[ 0 + n16][32 + quad * 8];
            O0 = __builtin_amdgcn_mfma_f32_16x16x32_bf16(a0, pb0, O0, 0, 0, 0);
            O0 = __builtin_amdgcn_mfma_f32_16x16x32_bf16(a1, pb1, O0, 0, 0, 0);
            a0 = *(const bf16x8*)&Vt[16 + n16][quad * 8];
            a1 = *(const bf16x8*)&Vt[16 + n16][32 + quad * 8];
            O1 = __builtin_amdgcn_mfma_f32_16x16x32_bf16(a0, pb0, O1, 0, 0, 0);
            O1 = __builtin_amdgcn_mfma_f32_16x16x32_bf16(a1, pb1, O1, 0, 0, 0);
            a0 = *(const bf16x8*)&Vt[32 + n16][quad * 8];
            a1 = *(const bf16x8*)&Vt[32 + n16][32 + quad * 8];
            O2 = __builtin_amdgcn_mfma_f32_16x16x32_bf16(a0, pb0, O2, 0, 0, 0);
            O2 = __builtin_amdgcn_mfma_f32_16x16x32_bf16(a1, pb1, O2, 0, 0, 0);
            a0 = *(const bf16x8*)&Vt[48 + n16][quad * 8];
            a1 = *(const bf16x8*)&Vt[48 + n16][32 + quad * 8];
            O3 = __builtin_amdgcn_mfma_f32_16x16x32_bf16(a0, pb0, O3, 0, 0, 0);
            O3 = __builtin_amdgcn_mfma_f32_16x16x32_bf16(a1, pb1, O3, 0, 0, 0);
        }
        __syncthreads();
    }

    // ---- epilogue: per-lane 1/l, fp16 stores ----
    const float linv = 1.0f / l_run;
    const size_t orow = (size_t)(bb * L_ + q0 + w16 + n16) * 1024 + hh * 64 + quad * 4;
    {
        f16x4 o;
        o = (f16x4){(_Float16)(O0[0]*linv), (_Float16)(O0[1]*linv),
                    (_Float16)(O0[2]*linv), (_Float16)(O0[3]*linv)};
        *(f16x4*)&h16[orow +  0] = o;
        o = (f16x4){(_Float16)(O1[0]*linv), (_Float16)(O1[1]*linv),
                    (_Float16)(O1[2]*linv), (_Float16)(O1[3]*linv)};
        *(f16x4*)&h16[orow + 16] = o;
        o = (f16x4){(_Float16)(O2[0]*linv), (_Float16)(O2[1]*linv),
                    (_Float16)(O2[2]*linv), (_Float16)(O2[3]*linv)};
        *(f16x4*)&h16[orow + 32] = o;
        o = (f16x4){(_Float16)(O3[0]*linv), (_Float16)(O3[1]*linv),
                    (_Float16)(O3[2]*linv), (_Float16)(O3[3]*linv)};
        *(f16x4*)&h16[orow + 48] = o;
    }
}

// ---------------------------------------------------------------------------
extern "C" void kernel_launch(void* const* d_in, const int* in_sizes, int n_in,
                              void* d_out, int out_size, void* d_ws, size_t ws_size,
                              hipStream_t stream)
{
    const float* x       = (const float*)d_in[0];
    const float* Wqkv    = (const float*)d_in[1];
    const float* bqkv    = (const float*)d_in[2];
    const float* q_gamma = (const float*)d_in[3];
    const float* k_gamma = (const float*)d_in[4];
    const float* Wout    = (const float*)d_in[5];
    const float* bout    = (const float*)d_in[6];
    float* out = (float*)d_out;

    uint8_t* ws = (uint8_t*)d_ws;
    _Float16* x16   = (_Float16*)(ws);                      // 16 MB
    _Float16* Wq16  = (_Float16*)(ws + (16ull << 20));      //  6 MB
    _Float16* Wo16  = (_Float16*)(ws + (22ull << 20));      //  2 MB
    __bf16*   qkv16 = (__bf16*)  (ws + (24ull << 20));      // 48 MB
    _Float16* h16   = (_Float16*)(ws + (72ull << 20));      // 16 MB
    __bf16*   vT    = (__bf16*)  (ws + (88ull << 20));      // 16 MB (total 104)

    // 1) convert x -> fp16; transpose+convert weights -> [N][K] fp16
    cvt_f16_kernel<<<(B_ * L_ * C_) / 1024, 256, 0, stream>>>(x, x16);
    tr_cvt_f16_kernel<<<dim3(3 * C_ / 64, C_ / 64), 256, 0, stream>>>(Wqkv, Wq16, C_, 3 * C_);
    tr_cvt_f16_kernel<<<dim3(C_ / 64, C_ / 64), 256, 0, stream>>>(Wout, Wo16, C_, C_);

    // 2) qkv = x @ Wqkv + bqkv  -> bf16
    gemm_f16_bt_kernel<1><<<dim3(3 * C_ / 128, B_ * L_ / 128), 256, 0, stream>>>(
        x16, Wq16, bqkv, qkv16, B_ * L_, 3 * C_, C_);

    // 3) RMS-norm q,k in place (1/sqrt(D) and log2e folded into q, sqrt(D) into k)
    rmsnorm_bf16_kernel<<<2 * B_ * L_ * H_ / 4, 256, 0, stream>>>(qkv16, q_gamma, k_gamma);

    // 4) V pre-transpose -> vT[b][h][d][l]
    tr_v_kernel<<<dim3(L_ / 64, B_ * H_), 256, 0, stream>>>(qkv16, vT);

    // 5) flash attention -> h16
    attn_mfma_kernel<<<B_ * H_ * (L_ / 64), 256, 0, stream>>>(qkv16, vT, h16);

    // 6) out = h @ Wout + bout  -> fp32
    gemm_f16_bt_kernel<0><<<dim3(C_ / 128, B_ * L_ / 128), 256, 0, stream>>>(
        h16, Wo16, bout, out, B_ * L_, C_, C_);
}

// Round 5
// 363.297 us; speedup vs baseline: 6.5033x; 1.1751x over previous
//
#include <hip/hip_runtime.h>
#include <hip/hip_bf16.h>
#include <cstdint>
#include <cstddef>

#define B_ 4
#define L_ 2048
#define C_ 1024
#define H_ 16
#define D_ 64

typedef __bf16    bf16x2 __attribute__((ext_vector_type(2)));
typedef __bf16    bf16x4 __attribute__((ext_vector_type(4)));
typedef __bf16    bf16x8 __attribute__((ext_vector_type(8)));
typedef _Float16  f16x4  __attribute__((ext_vector_type(4)));
typedef _Float16  f16x8  __attribute__((ext_vector_type(8)));
typedef float     f32x4  __attribute__((ext_vector_type(4)));

// async global->LDS, 16 B per lane. LDS dest = wave-uniform base + lane*16.
typedef const __attribute__((address_space(1))) uint32_t* gas_ptr;
typedef __attribute__((address_space(3))) uint32_t* las_ptr;
__device__ __forceinline__ void gl_lds16(const void* g, void* l) {
    __builtin_amdgcn_global_load_lds((gas_ptr)(uintptr_t)g,
                                     (las_ptr)(uintptr_t)l, 16, 0, 0);
}

// ---------------------------------------------------------------------------
// fp32 -> fp16 elementwise (4 elems/thread)
// ---------------------------------------------------------------------------
__global__ __launch_bounds__(256) void cvt_f16_kernel(
    const float* __restrict__ in, _Float16* __restrict__ out)
{
    int i = (blockIdx.x * 256 + threadIdx.x) * 4;
    float4 v = *(const float4*)&in[i];
    f16x4 o = {(_Float16)v.x, (_Float16)v.y, (_Float16)v.z, (_Float16)v.w};
    *(f16x4*)&out[i] = o;
}

// ---------------------------------------------------------------------------
// W [K][N] fp32 -> Wt [N][K] fp16 (LDS-tiled transpose, 64x64 tile)
// ---------------------------------------------------------------------------
__global__ __launch_bounds__(256) void tr_cvt_f16_kernel(
    const float* __restrict__ W, _Float16* __restrict__ Wt, int K, int N)
{
    __shared__ float tile[64][65];
    const int tid = threadIdx.x;
    const int k0 = blockIdx.y * 64, n0 = blockIdx.x * 64;
    for (int i = tid; i < 1024; i += 256) {
        int r = i >> 4, c4 = (i & 15) * 4;
        float4 v = *(const float4*)&W[(size_t)(k0 + r) * N + n0 + c4];
        tile[r][c4 + 0] = v.x; tile[r][c4 + 1] = v.y;
        tile[r][c4 + 2] = v.z; tile[r][c4 + 3] = v.w;
    }
    __syncthreads();
    for (int i = tid; i < 1024; i += 256) {
        int n = i >> 4, k4 = (i & 15) * 4;
        f16x4 o = {(_Float16)tile[k4 + 0][n], (_Float16)tile[k4 + 1][n],
                   (_Float16)tile[k4 + 2][n], (_Float16)tile[k4 + 3][n]};
        *(f16x4*)&Wt[(size_t)(n0 + n) * K + k0 + k4] = o;
    }
}

// ---------------------------------------------------------------------------
// fp16 MFMA GEMM (m97 structure) — unchanged from R3/R4.
// ---------------------------------------------------------------------------
template <int OUT_BF16>
__global__ __launch_bounds__(256) void gemm_f16_bt_kernel(
    const _Float16* __restrict__ A, const _Float16* __restrict__ Bt,
    const float* __restrict__ bias, void* __restrict__ Cout,
    int M, int N, int K)
{
    __shared__ __align__(16) _Float16 Ash[128 * 32];
    __shared__ __align__(16) _Float16 Bsh[128 * 32];

    const int tid  = threadIdx.x;
    const int lane = tid & 63;
    const int wv   = tid >> 6;
    const int wm   = wv & 1, wn = wv >> 1;
    const int n16  = lane & 15, quad = lane >> 4;
    const int brow = blockIdx.y * 128;
    const int bcol = blockIdx.x * 128;

    const int srow = lane >> 2;
    const int scol = (lane & 3) * 8;
    const _Float16* gA = A  + (size_t)(brow + wv * 32 + srow) * K + scol;
    const _Float16* gB = Bt + (size_t)(bcol + wv * 32 + srow) * K + scol;
    _Float16* lA0 = &Ash[wv * 1024];
    _Float16* lA1 = &Ash[wv * 1024 + 512];
    _Float16* lB0 = &Bsh[wv * 1024];
    _Float16* lB1 = &Bsh[wv * 1024 + 512];

    f32x4 acc[4][4] = {};

    for (int k0 = 0; k0 < K; k0 += 32) {
        gl_lds16(gA + k0,                  lA0);
        gl_lds16(gA + k0 + 16 * (size_t)K, lA1);
        gl_lds16(gB + k0,                  lB0);
        gl_lds16(gB + k0 + 16 * (size_t)K, lB1);
        __syncthreads();

        f16x8 ar[4], br[4];
        #pragma unroll
        for (int t = 0; t < 4; t++) {
            ar[t] = *(const f16x8*)&Ash[(wm * 64 + t * 16 + n16) * 32 + quad * 8];
            br[t] = *(const f16x8*)&Bsh[(wn * 64 + t * 16 + n16) * 32 + quad * 8];
        }
        #pragma unroll
        for (int i = 0; i < 4; i++)
            #pragma unroll
            for (int j = 0; j < 4; j++)
                acc[i][j] = __builtin_amdgcn_mfma_f32_16x16x32_f16(
                    ar[i], br[j], acc[i][j], 0, 0, 0);
        __syncthreads();
    }

    #pragma unroll
    for (int j = 0; j < 4; j++) {
        const int col = bcol + wn * 64 + j * 16 + n16;
        const float bv = bias[col];
        #pragma unroll
        for (int i = 0; i < 4; i++) {
            const int row0 = brow + wm * 64 + i * 16 + quad * 4;
            #pragma unroll
            for (int r = 0; r < 4; r++) {
                float v = acc[i][j][r] + bv;
                if (OUT_BF16)
                    ((__bf16*)Cout)[(size_t)(row0 + r) * N + col] = (__bf16)v;
                else
                    ((float*)Cout)[(size_t)(row0 + r) * N + col] = v;
            }
        }
    }
}

// ---------------------------------------------------------------------------
// Per-head RMS norm of q and k rows, in place on bf16 qkv.
// q scale folds 1/sqrt(D)*sqrt(D)=1 AND log2(e); k scale = sqrt(D) = 8.
// ---------------------------------------------------------------------------
__global__ __launch_bounds__(256) void rmsnorm_bf16_kernel(
    __bf16* __restrict__ qkv, const float* __restrict__ q_gamma,
    const float* __restrict__ k_gamma)
{
    const int lane = threadIdx.x & 63;
    const int wid = blockIdx.x * 4 + (threadIdx.x >> 6);
    const int NROWS = B_ * L_ * H_;
    int s, row;
    const float* gamma;
    float scl;
    if (wid < NROWS) { s = 0; row = wid;         gamma = q_gamma; scl = 1.44269504f; }
    else             { s = 1; row = wid - NROWS; gamma = k_gamma; scl = 8.0f; }
    const int h  = row & 15;
    const int bl = row >> 4;
    const size_t idx = ((size_t)bl * 3 + s) * 1024 + h * 64 + lane;
    float v = (float)qkv[idx];
    float ss = v * v;
    #pragma unroll
    for (int m = 1; m < 64; m <<= 1) ss += __shfl_xor(ss, m, 64);
    float denom = fmaxf(sqrtf(ss), 1e-12f);
    qkv[idx] = (__bf16)((v / denom) * gamma[h * 64 + lane] * scl);
}

// ---------------------------------------------------------------------------
// V pre-transpose: qkv v-part [b][l][h][d] -> vT[b][h][d][l] (bf16).
// ---------------------------------------------------------------------------
__global__ __launch_bounds__(256) void tr_v_kernel(
    const __bf16* __restrict__ qkv, __bf16* __restrict__ vT)
{
    __shared__ __bf16 t[64][72];
    const int tid = threadIdx.x;
    const int t0 = blockIdx.x * 64;
    const int bh = blockIdx.y;
    const int b = bh >> 4, h = bh & 15;
    for (int i = tid; i < 512; i += 256) {
        int r = i >> 3, d8 = (i & 7) * 8;
        *(bf16x8*)&t[r][d8] =
            *(const bf16x8*)&qkv[(size_t)(b * L_ + t0 + r) * 3072 + 2048 + h * 64 + d8];
    }
    __syncthreads();
    for (int i = tid; i < 512; i += 256) {
        int d = i & 63, k8 = (i >> 6) * 8;
        bf16x8 o;
        #pragma unroll
        for (int j = 0; j < 8; j++) o[j] = t[k8 + j][d];
        *(bf16x8*)&vT[((size_t)bh * 64 + d) * 2048 + t0 + k8] = o;
    }
}

// ---------------------------------------------------------------------------
// MFMA flash attention v3: Bq=128 (32 q-rows/wave as 2 q-groups of 16),
// no-max softmax (scores bounded: |s_log2| <= |q||k| = 1.443*8 = 11.6,
// exp2 <= 3e3, l <= 6.2e6 — far inside fp32; identical math to softmax).
//
// S^T = K @ Q^T (A=K rows, B=Q rows): lane holds 16 keys of ONE q-row per
// q-group; l-sum = in-lane adds + 2 shuffles. K/Vt A-frags are read once
// per wave and feed BOTH q-groups (halves the per-q-row LDS traffic vs R4).
// O^T = V^T @ P^T. Ps aliases Qs (Q frags hoisted to regs; each wave only
// touches its own 32 rows of the union region — no extra barrier needed).
// ---------------------------------------------------------------------------
__global__ __launch_bounds__(256) void attn_mfma_kernel(
    const __bf16* __restrict__ qkv, const __bf16* __restrict__ vT,
    _Float16* __restrict__ h16)
{
    const int tid  = threadIdx.x;
    const int lane = tid & 63;
    const int wv   = tid >> 6;
    const int n16  = lane & 15;
    const int quad = lane >> 4;
    const int qt = blockIdx.x & 15;        // 16 q-tiles of 128
    const int hh = (blockIdx.x >> 4) & 15;
    const int bb = blockIdx.x >> 8;
    const int q0 = qt * 128;
    const int w32 = wv * 32;
    const int bh = bb * 16 + hh;

    // QP: Qs then (after frag hoist) Ps. 128x72 + Ks 64x72 + Vt 64x72 = 36 KB
    __shared__ __align__(16) __bf16 smem[(128 + 64 + 64) * 72];
    __bf16* QP = smem;                 // [128][72]
    __bf16* Ksm = smem + 128 * 72;     // [64][72]
    __bf16* Vtm = smem + 192 * 72;     // [64][72]

    // ---- stage Q tile (pre-scaled by log2e in rmsnorm) ----
    #pragma unroll
    for (int t = 0; t < 4; t++) {
        int i = tid + t * 256;
        int r = i >> 3, d8 = (i & 7) * 8;
        *(bf16x8*)&QP[r * 72 + d8] =
            *(const bf16x8*)&qkv[(size_t)(bb * L_ + q0 + r) * 3072 + hh * 64 + d8];
    }
    __syncthreads();

    // hoisted Q B-frags: [qg][d-half]
    bf16x8 qf[2][2];
    #pragma unroll
    for (int qg = 0; qg < 2; qg++)
        #pragma unroll
        for (int hf = 0; hf < 2; hf++)
            qf[qg][hf] = *(const bf16x8*)&QP[(w32 + qg * 16 + n16) * 72 + hf * 32 + quad * 8];
    __syncthreads();   // everyone done reading Q before Ps overwrites

    f32x4 O[2][4] = {};
    float l_run[2] = {0.f, 0.f};

    const __bf16* kbase = &qkv[(size_t)(bb * L_) * 3072 + 1024 + hh * 64];
    const __bf16* vbase = &vT[(size_t)bh * 64 * 2048];

    for (int j0 = 0; j0 < L_; j0 += 64) {
        // ---- stage K rows (64x64) ----
        #pragma unroll
        for (int t = 0; t < 2; t++) {
            int i = tid + t * 256;
            int r = i >> 3, d8 = (i & 7) * 8;
            *(bf16x8*)&Ksm[r * 72 + d8] =
                *(const bf16x8*)&kbase[(size_t)(j0 + r) * 3072 + d8];
        }
        // ---- stage Vt rows (d-major, precomputed) ----
        #pragma unroll
        for (int t = 0; t < 2; t++) {
            int i = tid + t * 256;
            int d = i >> 3, k8 = (i & 7) * 8;
            *(bf16x8*)&Vtm[d * 72 + k8] =
                *(const bf16x8*)&vbase[(size_t)d * 2048 + j0 + k8];
        }
        __syncthreads();

        // ---- S^T = K @ Q^T : St[qg][kg], K-frags shared across q-groups ----
        f32x4 St[2][4] = {};
        #pragma unroll
        for (int kg = 0; kg < 4; kg++) {
            bf16x8 a0 = *(const bf16x8*)&Ksm[(kg * 16 + n16) * 72 + quad * 8];
            bf16x8 a1 = *(const bf16x8*)&Ksm[(kg * 16 + n16) * 72 + 32 + quad * 8];
            St[0][kg] = __builtin_amdgcn_mfma_f32_16x16x32_bf16(a0, qf[0][0], St[0][kg], 0, 0, 0);
            St[0][kg] = __builtin_amdgcn_mfma_f32_16x16x32_bf16(a1, qf[0][1], St[0][kg], 0, 0, 0);
            St[1][kg] = __builtin_amdgcn_mfma_f32_16x16x32_bf16(a0, qf[1][0], St[1][kg], 0, 0, 0);
            St[1][kg] = __builtin_amdgcn_mfma_f32_16x16x32_bf16(a1, qf[1][1], St[1][kg], 0, 0, 0);
        }

        // ---- no-max softmax: p = 2^s, accumulate l ----
        #pragma unroll
        for (int qg = 0; qg < 2; qg++) {
            const int prow = (w32 + qg * 16 + n16) * 72;
            float ts = 0.f;
            #pragma unroll
            for (int kg = 0; kg < 4; kg++) {
                float p0 = __builtin_amdgcn_exp2f(St[qg][kg][0]);
                float p1 = __builtin_amdgcn_exp2f(St[qg][kg][1]);
                float p2 = __builtin_amdgcn_exp2f(St[qg][kg][2]);
                float p3 = __builtin_amdgcn_exp2f(St[qg][kg][3]);
                bf16x4 t4 = {(__bf16)p0, (__bf16)p1, (__bf16)p2, (__bf16)p3};
                *(bf16x4*)&QP[prow + kg * 16 + quad * 4] = t4;
                ts += (p0 + p1) + (p2 + p3);
            }
            ts += __shfl_xor(ts, 16, 64);
            ts += __shfl_xor(ts, 32, 64);
            l_run[qg] += ts;
        }

        // ---- O^T += V^T @ P^T (Vt A-frags shared across q-groups) ----
        bf16x8 pf[2][2];
        #pragma unroll
        for (int qg = 0; qg < 2; qg++)
            #pragma unroll
            for (int kh = 0; kh < 2; kh++)
                pf[qg][kh] = *(const bf16x8*)&QP[(w32 + qg * 16 + n16) * 72 + kh * 32 + quad * 8];

        #pragma unroll
        for (int dg = 0; dg < 4; dg++) {
            bf16x8 v0 = *(const bf16x8*)&Vtm[(dg * 16 + n16) * 72 + quad * 8];
            bf16x8 v1 = *(const bf16x8*)&Vtm[(dg * 16 + n16) * 72 + 32 + quad * 8];
            O[0][dg] = __builtin_amdgcn_mfma_f32_16x16x32_bf16(v0, pf[0][0], O[0][dg], 0, 0, 0);
            O[0][dg] = __builtin_amdgcn_mfma_f32_16x16x32_bf16(v1, pf[0][1], O[0][dg], 0, 0, 0);
            O[1][dg] = __builtin_amdgcn_mfma_f32_16x16x32_bf16(v0, pf[1][0], O[1][dg], 0, 0, 0);
            O[1][dg] = __builtin_amdgcn_mfma_f32_16x16x32_bf16(v1, pf[1][1], O[1][dg], 0, 0, 0);
        }
        __syncthreads();
    }

    // ---- epilogue: O^T col = n16 = q-row, rows d = dg*16+quad*4+r ----
    #pragma unroll
    for (int qg = 0; qg < 2; qg++) {
        const float linv = 1.0f / l_run[qg];
        const int q = q0 + w32 + qg * 16 + n16;
        const size_t orow = (size_t)(bb * L_ + q) * 1024 + hh * 64 + quad * 4;
        #pragma unroll
        for (int dg = 0; dg < 4; dg++) {
            f16x4 o = {(_Float16)(O[qg][dg][0] * linv),
                       (_Float16)(O[qg][dg][1] * linv),
                       (_Float16)(O[qg][dg][2] * linv),
                       (_Float16)(O[qg][dg][3] * linv)};
            *(f16x4*)&h16[orow + dg * 16] = o;
        }
    }
}

// ---------------------------------------------------------------------------
extern "C" void kernel_launch(void* const* d_in, const int* in_sizes, int n_in,
                              void* d_out, int out_size, void* d_ws, size_t ws_size,
                              hipStream_t stream)
{
    const float* x       = (const float*)d_in[0];
    const float* Wqkv    = (const float*)d_in[1];
    const float* bqkv    = (const float*)d_in[2];
    const float* q_gamma = (const float*)d_in[3];
    const float* k_gamma = (const float*)d_in[4];
    const float* Wout    = (const float*)d_in[5];
    const float* bout    = (const float*)d_in[6];
    float* out = (float*)d_out;

    uint8_t* ws = (uint8_t*)d_ws;
    _Float16* x16   = (_Float16*)(ws);                      // 16 MB
    _Float16* Wq16  = (_Float16*)(ws + (16ull << 20));      //  6 MB
    _Float16* Wo16  = (_Float16*)(ws + (22ull << 20));      //  2 MB
    __bf16*   qkv16 = (__bf16*)  (ws + (24ull << 20));      // 48 MB
    _Float16* h16   = (_Float16*)(ws + (72ull << 20));      // 16 MB
    __bf16*   vT    = (__bf16*)  (ws + (88ull << 20));      // 16 MB (total 104)

    // 1) convert x -> fp16; transpose+convert weights -> [N][K] fp16
    cvt_f16_kernel<<<(B_ * L_ * C_) / 1024, 256, 0, stream>>>(x, x16);
    tr_cvt_f16_kernel<<<dim3(3 * C_ / 64, C_ / 64), 256, 0, stream>>>(Wqkv, Wq16, C_, 3 * C_);
    tr_cvt_f16_kernel<<<dim3(C_ / 64, C_ / 64), 256, 0, stream>>>(Wout, Wo16, C_, C_);

    // 2) qkv = x @ Wqkv + bqkv  -> bf16
    gemm_f16_bt_kernel<1><<<dim3(3 * C_ / 128, B_ * L_ / 128), 256, 0, stream>>>(
        x16, Wq16, bqkv, qkv16, B_ * L_, 3 * C_, C_);

    // 3) RMS-norm q,k in place (1/sqrt(D), log2e folded into q; sqrt(D) into k)
    rmsnorm_bf16_kernel<<<2 * B_ * L_ * H_ / 4, 256, 0, stream>>>(qkv16, q_gamma, k_gamma);

    // 4) V pre-transpose -> vT[b][h][d][l]
    tr_v_kernel<<<dim3(L_ / 64, B_ * H_), 256, 0, stream>>>(qkv16, vT);

    // 5) flash attention (Bq=128) -> h16
    attn_mfma_kernel<<<B_ * H_ * (L_ / 128), 256, 0, stream>>>(qkv16, vT, h16);

    // 6) out = h @ Wout + bout  -> fp32
    gemm_f16_bt_kernel<0><<<dim3(C_ / 128, B_ * L_ / 128), 256, 0, stream>>>(
        h16, Wo16, bout, out, B_ * L_, C_, C_);
}

// Round 6
// 317.170 us; speedup vs baseline: 7.4491x; 1.1454x over previous
//
#include <hip/hip_runtime.h>
#include <hip/hip_bf16.h>
#include <cstdint>
#include <cstddef>

#define B_ 4
#define L_ 2048
#define C_ 1024
#define H_ 16
#define D_ 64

typedef __bf16    bf16x2 __attribute__((ext_vector_type(2)));
typedef __bf16    bf16x4 __attribute__((ext_vector_type(4)));
typedef __bf16    bf16x8 __attribute__((ext_vector_type(8)));
typedef _Float16  f16x4  __attribute__((ext_vector_type(4)));
typedef _Float16  f16x8  __attribute__((ext_vector_type(8)));
typedef float     f32x4  __attribute__((ext_vector_type(4)));

// async global->LDS, 16 B per lane. LDS dest = wave-uniform base + lane*16.
typedef const __attribute__((address_space(1))) uint32_t* gas_ptr;
typedef __attribute__((address_space(3))) uint32_t* las_ptr;
__device__ __forceinline__ void gl_lds16(const void* g, void* l) {
    __builtin_amdgcn_global_load_lds((gas_ptr)(uintptr_t)g,
                                     (las_ptr)(uintptr_t)l, 16, 0, 0);
}

// ---------------------------------------------------------------------------
// prep kernel: region A = x fp32->fp16 (8192 blocks), region B = Wqkv
// transpose+cvt (768 blocks), region C = Wout transpose+cvt (256 blocks).
// ---------------------------------------------------------------------------
__global__ __launch_bounds__(256) void prep_kernel(
    const float* __restrict__ x, _Float16* __restrict__ x16,
    const float* __restrict__ Wqkv, _Float16* __restrict__ Wq16,
    const float* __restrict__ Wout, _Float16* __restrict__ Wo16)
{
    __shared__ float tile[64][65];
    int bid = blockIdx.x;
    const int tid = threadIdx.x;

    if (bid < 8192) {                      // cvt x
        int i = (bid * 256 + tid) * 4;
        float4 v = *(const float4*)&x[i];
        f16x4 o = {(_Float16)v.x, (_Float16)v.y, (_Float16)v.z, (_Float16)v.w};
        *(f16x4*)&x16[i] = o;
        return;
    }
    bid -= 8192;
    const float* W; _Float16* Wt; int N, tx, ty;
    if (bid < 768) { W = Wqkv; Wt = Wq16; N = 3072; tx = bid % 48; ty = bid / 48; }
    else { bid -= 768; W = Wout; Wt = Wo16; N = 1024; tx = bid % 16; ty = bid / 16; }
    const int K = 1024;
    const int k0 = ty * 64, n0 = tx * 64;
    for (int i = tid; i < 1024; i += 256) {
        int r = i >> 4, c4 = (i & 15) * 4;
        float4 v = *(const float4*)&W[(size_t)(k0 + r) * N + n0 + c4];
        tile[r][c4 + 0] = v.x; tile[r][c4 + 1] = v.y;
        tile[r][c4 + 2] = v.z; tile[r][c4 + 3] = v.w;
    }
    __syncthreads();
    for (int i = tid; i < 1024; i += 256) {
        int n = i >> 4, k4 = (i & 15) * 4;
        f16x4 o = {(_Float16)tile[k4 + 0][n], (_Float16)tile[k4 + 1][n],
                   (_Float16)tile[k4 + 2][n], (_Float16)tile[k4 + 3][n]};
        *(f16x4*)&Wt[(size_t)(n0 + n) * K + k0 + k4] = o;
    }
}

// ---------------------------------------------------------------------------
// fp16 MFMA GEMM (m97 structure).
// MODE 0: proj — fp32 out + bias.
// MODE 1: QKV fused — q/k tiles: bias + per-head RMS norm on fp32 acc
//   (q scale = log2e, k scale = sqrt(D)=8), write bf16 to qkv;
//   v tiles: bias, bf16, transpose via LDS (aliased over staging), write vT.
//   Head-row sumsq: one head = 4 regs x 16 lanes of a quad-row ->
//   4 in-lane FMAs + shuffles xor 1,2,4,8.
// ---------------------------------------------------------------------------
template <int MODE>
__global__ __launch_bounds__(256) void gemm_f16_bt_kernel(
    const _Float16* __restrict__ A, const _Float16* __restrict__ Bt,
    const float* __restrict__ bias, void* __restrict__ Cout,
    __bf16* __restrict__ vTout, const float* __restrict__ q_gamma,
    const float* __restrict__ k_gamma, int M, int N, int K)
{
    // MODE 1 needs 128x136 bf16 (34816 B) for the v transpose, aliased over
    // the 16 KB staging area. MODE 0 stays at 16 KB.
    __shared__ __align__(16) char smraw[MODE == 1 ? 34816 : 16384];
    _Float16* Ash = (_Float16*)smraw;
    _Float16* Bsh = Ash + 128 * 32;

    const int tid  = threadIdx.x;
    const int lane = tid & 63;
    const int wv   = tid >> 6;
    const int wm   = wv & 1, wn = wv >> 1;
    const int n16  = lane & 15, quad = lane >> 4;
    const int brow = blockIdx.y * 128;
    const int bcol = blockIdx.x * 128;

    const int srow = lane >> 2;
    const int scol = (lane & 3) * 8;
    const _Float16* gA = A  + (size_t)(brow + wv * 32 + srow) * K + scol;
    const _Float16* gB = Bt + (size_t)(bcol + wv * 32 + srow) * K + scol;
    _Float16* lA0 = &Ash[wv * 1024];
    _Float16* lA1 = &Ash[wv * 1024 + 512];
    _Float16* lB0 = &Bsh[wv * 1024];
    _Float16* lB1 = &Bsh[wv * 1024 + 512];

    f32x4 acc[4][4] = {};

    for (int k0 = 0; k0 < K; k0 += 32) {
        gl_lds16(gA + k0,                  lA0);
        gl_lds16(gA + k0 + 16 * (size_t)K, lA1);
        gl_lds16(gB + k0,                  lB0);
        gl_lds16(gB + k0 + 16 * (size_t)K, lB1);
        __syncthreads();

        f16x8 ar[4], br[4];
        #pragma unroll
        for (int t = 0; t < 4; t++) {
            ar[t] = *(const f16x8*)&Ash[(wm * 64 + t * 16 + n16) * 32 + quad * 8];
            br[t] = *(const f16x8*)&Bsh[(wn * 64 + t * 16 + n16) * 32 + quad * 8];
        }
        #pragma unroll
        for (int i = 0; i < 4; i++)
            #pragma unroll
            for (int j = 0; j < 4; j++)
                acc[i][j] = __builtin_amdgcn_mfma_f32_16x16x32_f16(
                    ar[i], br[j], acc[i][j], 0, 0, 0);
        __syncthreads();
    }

    if (MODE == 0) {
        #pragma unroll
        for (int j = 0; j < 4; j++) {
            const int col = bcol + wn * 64 + j * 16 + n16;
            const float bv = bias[col];
            #pragma unroll
            for (int i = 0; i < 4; i++) {
                const int row0 = brow + wm * 64 + i * 16 + quad * 4;
                #pragma unroll
                for (int r = 0; r < 4; r++)
                    ((float*)Cout)[(size_t)(row0 + r) * N + col] = acc[i][j][r] + bv;
            }
        }
        return;
    }

    // ---------------- MODE 1: fused QKV epilogue ----------------
    const int region = bcol >> 10;         // 0 = q, 1 = k, 2 = v
    float bj[4];
    #pragma unroll
    for (int j = 0; j < 4; j++) bj[j] = bias[bcol + wn * 64 + j * 16 + n16];

    if (region < 2) {
        const float* gamma = (region == 0) ? q_gamma : k_gamma;
        const float scl = (region == 0) ? 1.44269504f : 8.0f;  // log2e | sqrt(D)
        const int cb = (bcol & 1023) + wn * 64 + n16;          // head-local col
        float gj[4];
        #pragma unroll
        for (int j = 0; j < 4; j++) gj[j] = gamma[cb + j * 16];

        #pragma unroll
        for (int i = 0; i < 4; i++) {
            #pragma unroll
            for (int r = 0; r < 4; r++) {
                float v0 = acc[i][0][r] + bj[0];
                float v1 = acc[i][1][r] + bj[1];
                float v2 = acc[i][2][r] + bj[2];
                float v3 = acc[i][3][r] + bj[3];
                float ss = v0 * v0 + v1 * v1 + v2 * v2 + v3 * v3;
                ss += __shfl_xor(ss, 1, 64);
                ss += __shfl_xor(ss, 2, 64);
                ss += __shfl_xor(ss, 4, 64);
                ss += __shfl_xor(ss, 8, 64);
                const float sc = scl / fmaxf(sqrtf(ss), 1e-12f);
                const int row = brow + wm * 64 + i * 16 + quad * 4 + r;
                __bf16* op = (__bf16*)Cout + (size_t)row * 3072 + bcol + wn * 64 + n16;
                op[ 0] = (__bf16)(v0 * gj[0] * sc);
                op[16] = (__bf16)(v1 * gj[1] * sc);
                op[32] = (__bf16)(v2 * gj[2] * sc);
                op[48] = (__bf16)(v3 * gj[3] * sc);
            }
        }
    } else {
        // v region: bias + bf16, transpose via LDS, store to vT[b][h][d][l]
        __syncthreads();                       // staging reads done; reuse LDS
        __bf16* LT = (__bf16*)smraw;           // [col 0..127][row 0..127] s=136
        #pragma unroll
        for (int i = 0; i < 4; i++)
            #pragma unroll
            for (int j = 0; j < 4; j++) {
                const int col = wn * 64 + j * 16 + n16;
                const int row0 = wm * 64 + i * 16 + quad * 4;
                bf16x4 t4 = {(__bf16)(acc[i][j][0] + bj[j]),
                             (__bf16)(acc[i][j][1] + bj[j]),
                             (__bf16)(acc[i][j][2] + bj[j]),
                             (__bf16)(acc[i][j][3] + bj[j])};
                *(bf16x4*)&LT[col * 136 + row0] = t4;
            }
        __syncthreads();
        // coalesced store: thread -> (d = tid>>1, token-half = tid&1)
        const int d = tid >> 1, hf = tid & 1;
        const int bidx = brow >> 11;           // batch
        const int l0 = (brow & 2047) + hf * 64;
        const int head = ((bcol - 2048) >> 6) + (d >> 6);
        const size_t vb = (((size_t)(bidx * 16 + head)) * 64 + (d & 63)) * 2048 + l0;
        #pragma unroll
        for (int u = 0; u < 8; u++)
            *(bf16x8*)&vTout[vb + u * 8] = *(const bf16x8*)&LT[d * 136 + hf * 64 + u * 8];
    }
}

// ---------------------------------------------------------------------------
// MFMA flash attention v3 (unchanged from R5): Bq=128, no-max softmax
// (|s_log2| <= 1.443*8 = 11.6 -> exp2 <= 3e3, l <= 6.2e6, safe in fp32).
// S^T = K @ Q^T; O^T = V^T @ P^T; Ps aliases Qs after frag hoist.
// ---------------------------------------------------------------------------
__global__ __launch_bounds__(256) void attn_mfma_kernel(
    const __bf16* __restrict__ qkv, const __bf16* __restrict__ vT,
    _Float16* __restrict__ h16)
{
    const int tid  = threadIdx.x;
    const int lane = tid & 63;
    const int wv   = tid >> 6;
    const int n16  = lane & 15;
    const int quad = lane >> 4;
    const int qt = blockIdx.x & 15;
    const int hh = (blockIdx.x >> 4) & 15;
    const int bb = blockIdx.x >> 8;
    const int q0 = qt * 128;
    const int w32 = wv * 32;
    const int bh = bb * 16 + hh;

    __shared__ __align__(16) __bf16 smem[(128 + 64 + 64) * 72];
    __bf16* QP  = smem;
    __bf16* Ksm = smem + 128 * 72;
    __bf16* Vtm = smem + 192 * 72;

    #pragma unroll
    for (int t = 0; t < 4; t++) {
        int i = tid + t * 256;
        int r = i >> 3, d8 = (i & 7) * 8;
        *(bf16x8*)&QP[r * 72 + d8] =
            *(const bf16x8*)&qkv[(size_t)(bb * L_ + q0 + r) * 3072 + hh * 64 + d8];
    }
    __syncthreads();

    bf16x8 qf[2][2];
    #pragma unroll
    for (int qg = 0; qg < 2; qg++)
        #pragma unroll
        for (int hf = 0; hf < 2; hf++)
            qf[qg][hf] = *(const bf16x8*)&QP[(w32 + qg * 16 + n16) * 72 + hf * 32 + quad * 8];
    __syncthreads();

    f32x4 O[2][4] = {};
    float l_run[2] = {0.f, 0.f};

    const __bf16* kbase = &qkv[(size_t)(bb * L_) * 3072 + 1024 + hh * 64];
    const __bf16* vbase = &vT[(size_t)bh * 64 * 2048];

    for (int j0 = 0; j0 < L_; j0 += 64) {
        #pragma unroll
        for (int t = 0; t < 2; t++) {
            int i = tid + t * 256;
            int r = i >> 3, d8 = (i & 7) * 8;
            *(bf16x8*)&Ksm[r * 72 + d8] =
                *(const bf16x8*)&kbase[(size_t)(j0 + r) * 3072 + d8];
        }
        #pragma unroll
        for (int t = 0; t < 2; t++) {
            int i = tid + t * 256;
            int d = i >> 3, k8 = (i & 7) * 8;
            *(bf16x8*)&Vtm[d * 72 + k8] =
                *(const bf16x8*)&vbase[(size_t)d * 2048 + j0 + k8];
        }
        __syncthreads();

        f32x4 St[2][4] = {};
        #pragma unroll
        for (int kg = 0; kg < 4; kg++) {
            bf16x8 a0 = *(const bf16x8*)&Ksm[(kg * 16 + n16) * 72 + quad * 8];
            bf16x8 a1 = *(const bf16x8*)&Ksm[(kg * 16 + n16) * 72 + 32 + quad * 8];
            St[0][kg] = __builtin_amdgcn_mfma_f32_16x16x32_bf16(a0, qf[0][0], St[0][kg], 0, 0, 0);
            St[0][kg] = __builtin_amdgcn_mfma_f32_16x16x32_bf16(a1, qf[0][1], St[0][kg], 0, 0, 0);
            St[1][kg] = __builtin_amdgcn_mfma_f32_16x16x32_bf16(a0, qf[1][0], St[1][kg], 0, 0, 0);
            St[1][kg] = __builtin_amdgcn_mfma_f32_16x16x32_bf16(a1, qf[1][1], St[1][kg], 0, 0, 0);
        }

        #pragma unroll
        for (int qg = 0; qg < 2; qg++) {
            const int prow = (w32 + qg * 16 + n16) * 72;
            float ts = 0.f;
            #pragma unroll
            for (int kg = 0; kg < 4; kg++) {
                float p0 = __builtin_amdgcn_exp2f(St[qg][kg][0]);
                float p1 = __builtin_amdgcn_exp2f(St[qg][kg][1]);
                float p2 = __builtin_amdgcn_exp2f(St[qg][kg][2]);
                float p3 = __builtin_amdgcn_exp2f(St[qg][kg][3]);
                bf16x4 t4 = {(__bf16)p0, (__bf16)p1, (__bf16)p2, (__bf16)p3};
                *(bf16x4*)&QP[prow + kg * 16 + quad * 4] = t4;
                ts += (p0 + p1) + (p2 + p3);
            }
            ts += __shfl_xor(ts, 16, 64);
            ts += __shfl_xor(ts, 32, 64);
            l_run[qg] += ts;
        }

        bf16x8 pf[2][2];
        #pragma unroll
        for (int qg = 0; qg < 2; qg++)
            #pragma unroll
            for (int kh = 0; kh < 2; kh++)
                pf[qg][kh] = *(const bf16x8*)&QP[(w32 + qg * 16 + n16) * 72 + kh * 32 + quad * 8];

        #pragma unroll
        for (int dg = 0; dg < 4; dg++) {
            bf16x8 v0 = *(const bf16x8*)&Vtm[(dg * 16 + n16) * 72 + quad * 8];
            bf16x8 v1 = *(const bf16x8*)&Vtm[(dg * 16 + n16) * 72 + 32 + quad * 8];
            O[0][dg] = __builtin_amdgcn_mfma_f32_16x16x32_bf16(v0, pf[0][0], O[0][dg], 0, 0, 0);
            O[0][dg] = __builtin_amdgcn_mfma_f32_16x16x32_bf16(v1, pf[0][1], O[0][dg], 0, 0, 0);
            O[1][dg] = __builtin_amdgcn_mfma_f32_16x16x32_bf16(v0, pf[1][0], O[1][dg], 0, 0, 0);
            O[1][dg] = __builtin_amdgcn_mfma_f32_16x16x32_bf16(v1, pf[1][1], O[1][dg], 0, 0, 0);
        }
        __syncthreads();
    }

    #pragma unroll
    for (int qg = 0; qg < 2; qg++) {
        const float linv = 1.0f / l_run[qg];
        const int q = q0 + w32 + qg * 16 + n16;
        const size_t orow = (size_t)(bb * L_ + q) * 1024 + hh * 64 + quad * 4;
        #pragma unroll
        for (int dg = 0; dg < 4; dg++) {
            f16x4 o = {(_Float16)(O[qg][dg][0] * linv),
                       (_Float16)(O[qg][dg][1] * linv),
                       (_Float16)(O[qg][dg][2] * linv),
                       (_Float16)(O[qg][dg][3] * linv)};
            *(f16x4*)&h16[orow + dg * 16] = o;
        }
    }
}

// ---------------------------------------------------------------------------
extern "C" void kernel_launch(void* const* d_in, const int* in_sizes, int n_in,
                              void* d_out, int out_size, void* d_ws, size_t ws_size,
                              hipStream_t stream)
{
    const float* x       = (const float*)d_in[0];
    const float* Wqkv    = (const float*)d_in[1];
    const float* bqkv    = (const float*)d_in[2];
    const float* q_gamma = (const float*)d_in[3];
    const float* k_gamma = (const float*)d_in[4];
    const float* Wout    = (const float*)d_in[5];
    const float* bout    = (const float*)d_in[6];
    float* out = (float*)d_out;

    uint8_t* ws = (uint8_t*)d_ws;
    _Float16* x16   = (_Float16*)(ws);                      // 16 MB
    _Float16* Wq16  = (_Float16*)(ws + (16ull << 20));      //  6 MB
    _Float16* Wo16  = (_Float16*)(ws + (22ull << 20));      //  2 MB
    __bf16*   qkv16 = (__bf16*)  (ws + (24ull << 20));      // 48 MB (q,k used)
    _Float16* h16   = (_Float16*)(ws + (72ull << 20));      // 16 MB
    __bf16*   vT    = (__bf16*)  (ws + (88ull << 20));      // 16 MB (total 104)

    // 1) prep: x->fp16, W transposes (one launch, 3 regions)
    prep_kernel<<<8192 + 768 + 256, 256, 0, stream>>>(x, x16, Wqkv, Wq16, Wout, Wo16);

    // 2) fused QKV: GEMM + bias + RMS-norm (q,k -> qkv16 bf16) + V transpose
    //    (v -> vT), scales folded (q: log2e, k: sqrt(D))
    gemm_f16_bt_kernel<1><<<dim3(3 * C_ / 128, B_ * L_ / 128), 256, 0, stream>>>(
        x16, Wq16, bqkv, qkv16, vT, q_gamma, k_gamma, B_ * L_, 3 * C_, C_);

    // 3) flash attention (Bq=128) -> h16
    attn_mfma_kernel<<<B_ * H_ * (L_ / 128), 256, 0, stream>>>(qkv16, vT, h16);

    // 4) out = h @ Wout + bout -> fp32
    gemm_f16_bt_kernel<0><<<dim3(C_ / 128, B_ * L_ / 128), 256, 0, stream>>>(
        h16, Wo16, bout, out, nullptr, nullptr, nullptr, B_ * L_, C_, C_);
}